// Round 5
// baseline (364.698 us; speedup 1.0000x reference)
//
#include <hip/hip_runtime.h>
#include <hip/hip_bf16.h>

#define DIM 128

typedef short s16x8 __attribute__((ext_vector_type(8)));
typedef float f32x4 __attribute__((ext_vector_type(4)));

__device__ __forceinline__ ushort f2b(float f) {
    __hip_bfloat16 h = __float2bfloat16(f);
    return *reinterpret_cast<ushort*>(&h);
}
__device__ __forceinline__ uint pk2(float a, float b) {
    return (uint)f2b(a) | ((uint)f2b(b) << 16);
}
__device__ __forceinline__ float bl(uint u) { return __uint_as_float(u << 16); }
__device__ __forceinline__ float bh(uint u) { return __uint_as_float(u & 0xffff0000u); }

// Swizzled byte address inside a [rows][128 bf16] LDS tile (256B rows).
__device__ __forceinline__ int swz(int row, int kelem) {
    int b = row * 256 + kelem * 2;
    return b ^ ((row & 7) << 4);
}
__device__ __forceinline__ s16x8 read_frag(const char* lds, int row, int k0) {
    return *(const s16x8*)(lds + swz(row, k0));
}

// Wt[n][k] = bf16(W[k][n]) in LDS, swizzled.
__device__ __forceinline__ void build_wt(const float* __restrict__ W, char* lds) {
    const int t = threadIdx.x;
    const int n = t & 127;
    const int kbase = (t >> 7) * 64;
#pragma unroll
    for (int c = 0; c < 8; ++c) {
        const int k0 = kbase + c * 8;
        float v[8];
#pragma unroll
        for (int j = 0; j < 8; ++j) v[j] = W[(size_t)(k0 + j) * 128 + n];
        uint4 u;
        u.x = pk2(v[0], v[1]); u.y = pk2(v[2], v[3]);
        u.z = pk2(v[4], v[5]); u.w = pk2(v[6], v[7]);
        *(uint4*)(lds + swz(n, k0)) = u;
    }
}

__device__ __forceinline__ void stage_f32(const float* __restrict__ src, int r0, int N, char* lds) {
    const int t = threadIdx.x;
    const int r = t >> 2;
    const int k0 = (t & 3) * 32;
    const int row = r0 + r;
#pragma unroll
    for (int c = 0; c < 4; ++c) {
        uint4 u = make_uint4(0, 0, 0, 0);
        if (row < N) {
            const float4 f0 = *(const float4*)&src[(size_t)row * 128 + k0 + c * 8];
            const float4 f1 = *(const float4*)&src[(size_t)row * 128 + k0 + c * 8 + 4];
            u.x = pk2(f0.x, f0.y); u.y = pk2(f0.z, f0.w);
            u.z = pk2(f1.x, f1.y); u.w = pk2(f1.z, f1.w);
        }
        *(uint4*)(lds + swz(r, k0 + c * 8)) = u;
    }
}

__device__ __forceinline__ void stage_b16(const ushort* __restrict__ src, int r0, int N, char* lds) {
    const int t = threadIdx.x;
    const int r = t >> 2;
    const int k0 = (t & 3) * 32;
    const int row = r0 + r;
#pragma unroll
    for (int c = 0; c < 4; ++c) {
        uint4 u = make_uint4(0, 0, 0, 0);
        if (row < N) u = *(const uint4*)&src[(size_t)row * 128 + k0 + c * 8];
        *(uint4*)(lds + swz(r, k0 + c * 8)) = u;
    }
}

__device__ __forceinline__ void compute_store(
    const s16x8 af[4], const s16x8 b[2][4], ushort* __restrict__ out,
    int r0, int rt, int w, int lr, int lg, int N)
{
#pragma unroll
    for (int ct = 0; ct < 2; ++ct) {
        f32x4 acc = {0.f, 0.f, 0.f, 0.f};
#pragma unroll
        for (int kb = 0; kb < 4; ++kb)
            acc = __builtin_amdgcn_mfma_f32_16x16x32_bf16(af[kb], b[ct][kb], acc, 0, 0, 0);
        const int col = w * 32 + ct * 16 + lr;
        const int rbase = r0 + rt * 16 + 4 * lg;
#pragma unroll
        for (int j = 0; j < 4; ++j)
            if (rbase + j < N) out[(size_t)(rbase + j) * 128 + col] = f2b(acc[j]);
    }
}

// ---------------------------------------------------------------------------
// proj body: one 64-row tile of K/Q/V = x @ {Wk,Wq,Wv} + fused kwa.
// ---------------------------------------------------------------------------
__device__ void proj_body(
    const float* __restrict__ x,
    const float* __restrict__ Wk, const float* __restrict__ Wq, const float* __restrict__ Wv,
    const float* __restrict__ Wa,
    ushort* __restrict__ K, ushort* __restrict__ Q, ushort* __restrict__ V,
    float* __restrict__ kwa, int N, int tile,
    char* wt, char* at, float (*kwp)[64][4])
{
    const int t = threadIdx.x, w = t >> 6, l = t & 63;
    const int lr = l & 15, lg = l >> 4;

    s16x8 bK[2][4], bQ[2][4], bV[2][4];

    build_wt(Wk, wt);
    __syncthreads();
#pragma unroll
    for (int ct = 0; ct < 2; ++ct)
#pragma unroll
        for (int kb = 0; kb < 4; ++kb)
            bK[ct][kb] = read_frag(wt, w * 32 + ct * 16 + lr, kb * 32 + 8 * lg);
    __syncthreads();
    build_wt(Wq, wt);
    __syncthreads();
#pragma unroll
    for (int ct = 0; ct < 2; ++ct)
#pragma unroll
        for (int kb = 0; kb < 4; ++kb)
            bQ[ct][kb] = read_frag(wt, w * 32 + ct * 16 + lr, kb * 32 + 8 * lg);
    __syncthreads();
    build_wt(Wv, wt);
    __syncthreads();
#pragma unroll
    for (int ct = 0; ct < 2; ++ct)
#pragma unroll
        for (int kb = 0; kb < 4; ++kb)
            bV[ct][kb] = read_frag(wt, w * 32 + ct * 16 + lr, kb * 32 + 8 * lg);

    const int col0 = w * 32 + lr, col1 = col0 + 16;
    const float4 waA = *(const float4*)&Wa[col0 * 4];
    const float4 waB = *(const float4*)&Wa[col1 * 4];

    const int r0 = tile << 6;
    __syncthreads();
    stage_f32(x, r0, N, at);
    __syncthreads();
#pragma unroll
    for (int rt = 0; rt < 4; ++rt) {
        s16x8 af[4];
#pragma unroll
        for (int kb = 0; kb < 4; ++kb)
            af[kb] = read_frag(at, rt * 16 + lr, kb * 32 + 8 * lg);
        const int rbase = r0 + rt * 16 + 4 * lg;

        f32x4 aK[2];
#pragma unroll
        for (int ct = 0; ct < 2; ++ct) {
            aK[ct] = (f32x4){0.f, 0.f, 0.f, 0.f};
#pragma unroll
            for (int kb = 0; kb < 4; ++kb)
                aK[ct] = __builtin_amdgcn_mfma_f32_16x16x32_bf16(af[kb], bK[ct][kb], aK[ct], 0, 0, 0);
        }
#pragma unroll
        for (int ct = 0; ct < 2; ++ct) {
            const int col = ct ? col1 : col0;
#pragma unroll
            for (int j = 0; j < 4; ++j)
                if (rbase + j < N) K[(size_t)(rbase + j) * 128 + col] = f2b(aK[ct][j]);
        }
#pragma unroll
        for (int j = 0; j < 4; ++j) {
            float p0 = aK[0][j] * waA.x + aK[1][j] * waB.x;
            float p1 = aK[0][j] * waA.y + aK[1][j] * waB.y;
            float p2 = aK[0][j] * waA.z + aK[1][j] * waB.z;
            float p3 = aK[0][j] * waA.w + aK[1][j] * waB.w;
#pragma unroll
            for (int off = 8; off; off >>= 1) {
                p0 += __shfl_xor(p0, off);
                p1 += __shfl_xor(p1, off);
                p2 += __shfl_xor(p2, off);
                p3 += __shfl_xor(p3, off);
            }
            if (lr == 0) {
                kwp[w][rt * 16 + 4 * lg + j][0] = p0;
                kwp[w][rt * 16 + 4 * lg + j][1] = p1;
                kwp[w][rt * 16 + 4 * lg + j][2] = p2;
                kwp[w][rt * 16 + 4 * lg + j][3] = p3;
            }
        }
        compute_store(af, bQ, Q, r0, rt, w, lr, lg, N);
        compute_store(af, bV, V, r0, rt, w, lr, lg, N);
    }
    __syncthreads();
    if (t < 64 && r0 + t < N) {
        const float s0 = kwp[0][t][0] + kwp[1][t][0] + kwp[2][t][0] + kwp[3][t][0];
        const float s1 = kwp[0][t][1] + kwp[1][t][1] + kwp[2][t][1] + kwp[3][t][1];
        const float s2 = kwp[0][t][2] + kwp[1][t][2] + kwp[2][t][2] + kwp[3][t][2];
        const float s3 = kwp[0][t][3] + kwp[1][t][3] + kwp[2][t][3] + kwp[3][t][3];
        *(float4*)&kwa[(size_t)(r0 + t) * 4] = make_float4(s0, s1, s2, s3);
    }
}

// ---------------------------------------------------------------------------
// fused1: [0,ntu) proj_user tiles | [ntu,ntu+nti) proj_item | rest: hist
// ---------------------------------------------------------------------------
__global__ __launch_bounds__(256) void fused_proj_hist(
    const float* __restrict__ xu,
    const float* __restrict__ Wku, const float* __restrict__ Wqu, const float* __restrict__ Wvu,
    const float* __restrict__ Waui,
    ushort* __restrict__ Ku, ushort* __restrict__ Qu, ushort* __restrict__ Vu,
    float* __restrict__ kwa_u, int n_user, int ntu,
    const float* __restrict__ xi,
    const float* __restrict__ Wki, const float* __restrict__ Wqi, const float* __restrict__ Wvi,
    const float* __restrict__ Waiu,
    ushort* __restrict__ Ki, ushort* __restrict__ Qi, ushort* __restrict__ Vi,
    float* __restrict__ kwa_i, int n_item, int nti,
    const int* __restrict__ dst_i, const int* __restrict__ dst_u,
    int* __restrict__ cnt, int E)
{
    __shared__ char wt[32768];
    __shared__ char at[16384];
    __shared__ float kwp[4][64][4];
    const int b = blockIdx.x;

    if (b < ntu) {
        proj_body(xu, Wku, Wqu, Wvu, Waui, Ku, Qu, Vu, kwa_u, n_user, b, wt, at, kwp);
    } else if (b < ntu + nti) {
        proj_body(xi, Wki, Wqi, Wvi, Waiu, Ki, Qi, Vi, kwa_i, n_item, b - ntu, wt, at, kwp);
    } else {
        const int gid = (b - ntu - nti) * 256 + threadIdx.x;
        if (gid < E) atomicAdd(&cnt[dst_i[gid]], 1);
        else if (gid < 2 * E) atomicAdd(&cnt[n_item + dst_u[gid - E]], 1);
    }
}

// ---------------------------------------------------------------------------
__global__ __launch_bounds__(256) void alloc_kernel(
    const int* __restrict__ cnt, int* __restrict__ base,
    int* __restrict__ fill, int* __restrict__ cursor, int n)
{
    const int d = blockIdx.x * blockDim.x + threadIdx.x;
    const int lane = threadIdx.x & 63;
    int c = (d < n) ? cnt[d] : 0;
    int sc = c;
#pragma unroll
    for (int off = 1; off < 64; off <<= 1) {
        int t = __shfl_up(sc, off);
        if (lane >= off) sc += t;
    }
    const int total = __shfl(sc, 63);
    int wb = 0;
    if (lane == 63) wb = atomicAdd(cursor, total);
    wb = __shfl(wb, 63);
    if (d < n) {
        const int b = wb + sc - c;
        base[d] = b;
        fill[d] = b;
    }
}

__global__ __launch_bounds__(256) void scatter_kernel(
    const int* __restrict__ ei_ui, const int* __restrict__ ei_iu,
    int* __restrict__ fill, int* __restrict__ bucket, int ni, int E)
{
    const int e = blockIdx.x * blockDim.x + threadIdx.x;
    if (e < E) {
        const int pos = atomicAdd(&fill[ei_ui[E + e]], 1);
        bucket[pos] = ei_ui[e];
    } else if (e < 2 * E) {
        const int pos = atomicAdd(&fill[ni + ei_iu[E + e - E]], 1);
        bucket[pos] = ei_iu[e - E];
    }
}

// ---------------------------------------------------------------------------
// agg2: one wave per dst over the CONCATENATED dst space (items then users).
// 4-wide predicated unroll; no atomics; single write per row.
// ---------------------------------------------------------------------------
__global__ __launch_bounds__(256) void agg2_kernel(
    const int* __restrict__ base, const int* __restrict__ cnt, const int* __restrict__ bsrc,
    const ushort* __restrict__ Ku, const ushort* __restrict__ Qi, const ushort* __restrict__ Vu,
    const float* __restrict__ kwa_u, ushort* __restrict__ msgA,
    const ushort* __restrict__ Ki, const ushort* __restrict__ Qu, const ushort* __restrict__ Vi,
    const float* __restrict__ kwa_i, ushort* __restrict__ msgB,
    int n_item, int ntot)
{
    const int widx = (int)((blockIdx.x * blockDim.x + threadIdx.x) >> 6);
    if (widx >= ntot) return;
    const bool item_side = widx < n_item;
    const int d = item_side ? widx : widx - n_item;
    const ushort* K  = item_side ? Ku : Ki;
    const ushort* Q  = item_side ? Qi : Qu;
    const ushort* V  = item_side ? Vu : Vi;
    const float* kwa = item_side ? kwa_u : kwa_i;
    ushort* msg      = item_side ? msgA : msgB;

    const int l = threadIdx.x & 63;
    const int h = l >> 4;
    const float inv = 0.17677669529663687f;   // 1/sqrt(32)
    const uint qu = *(const uint*)&Q[(size_t)d * 128 + 2 * l];
    const float qx = bl(qu), qy = bh(qu);
    const int b = base[widx], c = cnt[widx];
    float mx = 0.f, my = 0.f;

    for (int i = 0; i < c; i += 4) {
        const int s0 = bsrc[b + i];
        const int s1 = (i + 1 < c) ? bsrc[b + i + 1] : s0;
        const int s2 = (i + 2 < c) ? bsrc[b + i + 2] : s0;
        const int s3 = (i + 3 < c) ? bsrc[b + i + 3] : s0;

        const uint ku0 = *(const uint*)&K[(size_t)s0 * 128 + 2 * l];
        const uint ku1 = *(const uint*)&K[(size_t)s1 * 128 + 2 * l];
        const uint ku2 = *(const uint*)&K[(size_t)s2 * 128 + 2 * l];
        const uint ku3 = *(const uint*)&K[(size_t)s3 * 128 + 2 * l];
        const uint vu0 = *(const uint*)&V[(size_t)s0 * 128 + 2 * l];
        const uint vu1 = *(const uint*)&V[(size_t)s1 * 128 + 2 * l];
        const uint vu2 = *(const uint*)&V[(size_t)s2 * 128 + 2 * l];
        const uint vu3 = *(const uint*)&V[(size_t)s3 * 128 + 2 * l];
        const float kw0 = kwa[(size_t)s0 * 4 + h];
        const float kw1 = kwa[(size_t)s1 * 4 + h];
        const float kw2 = kwa[(size_t)s2 * 4 + h];
        const float kw3 = kwa[(size_t)s3 * 4 + h];

        float p0 = bl(ku0) * qx + bh(ku0) * qy;
        float p1 = bl(ku1) * qx + bh(ku1) * qy;
        float p2 = bl(ku2) * qx + bh(ku2) * qy;
        float p3 = bl(ku3) * qx + bh(ku3) * qy;
#pragma unroll
        for (int off = 8; off; off >>= 1) {
            p0 += __shfl_xor(p0, off);
            p1 += __shfl_xor(p1, off);
            p2 += __shfl_xor(p2, off);
            p3 += __shfl_xor(p3, off);
        }
        const float e0 = __expf(p0 * inv + kw0);
        const float e1 = __expf(p1 * inv + kw1);
        const float e2 = __expf(p2 * inv + kw2);
        const float e3 = __expf(p3 * inv + kw3);
        float es0 = e0 + __shfl_xor(e0, 16);
        float es1 = e1 + __shfl_xor(e1, 16);
        float es2 = e2 + __shfl_xor(e2, 16);
        float es3 = e3 + __shfl_xor(e3, 16);
        es0 += __shfl_xor(es0, 32);
        es1 += __shfl_xor(es1, 32);
        es2 += __shfl_xor(es2, 32);
        es3 += __shfl_xor(es3, 32);
        const float a0 = __fdividef(e0, es0);
        const float a1 = (i + 1 < c) ? __fdividef(e1, es1) : 0.f;
        const float a2 = (i + 2 < c) ? __fdividef(e2, es2) : 0.f;
        const float a3 = (i + 3 < c) ? __fdividef(e3, es3) : 0.f;

        mx += a0 * bl(vu0) + a1 * bl(vu1) + a2 * bl(vu2) + a3 * bl(vu3);
        my += a0 * bh(vu0) + a1 * bh(vu1) + a2 * bh(vu2) + a3 * bh(vu3);
    }
    *(uint*)&msg[(size_t)d * 128 + 2 * l] = pk2(mx, my);
}

// ---------------------------------------------------------------------------
// post body: one 64-row tile of LN(((A@Wm)*rs+bm)@Wg + bg + resid)*g + b
// ---------------------------------------------------------------------------
__device__ void post_body(
    const ushort* __restrict__ A, const int* __restrict__ deg,
    const float* __restrict__ Wm, const float* __restrict__ bm,
    const float* __restrict__ Wg, const float* __restrict__ bg,
    const float* __restrict__ resid, const float* __restrict__ gamma,
    const float* __restrict__ beta, float* __restrict__ out, int N, int tile,
    char* wt, char* at, float2 (*part)[64], float2* lnp)
{
    const int t = threadIdx.x, w = t >> 6, l = t & 63;
    const int lr = l & 15, lg = l >> 4;

    s16x8 B1[2][4], B2[2][4];
    build_wt(Wm, wt);
    __syncthreads();
#pragma unroll
    for (int ct = 0; ct < 2; ++ct)
#pragma unroll
        for (int kb = 0; kb < 4; ++kb)
            B1[ct][kb] = read_frag(wt, w * 32 + ct * 16 + lr, kb * 32 + 8 * lg);
    __syncthreads();
    build_wt(Wg, wt);
    __syncthreads();
#pragma unroll
    for (int ct = 0; ct < 2; ++ct)
#pragma unroll
        for (int kb = 0; kb < 4; ++kb)
            B2[ct][kb] = read_frag(wt, w * 32 + ct * 16 + lr, kb * 32 + 8 * lg);

    const int col0 = w * 32 + lr, col1 = col0 + 16;
    const float bm0 = bm[col0], bm1 = bm[col1];
    const float bg0 = bg[col0], bg1 = bg[col1];
    const float g0 = gamma[col0], g1 = gamma[col1];
    const float be0 = beta[col0], be1 = beta[col1];

    const int r0 = tile << 6;
    __syncthreads();
    stage_b16(A, r0, N, at);
    __syncthreads();

    // Stage 1: tmp = A@Wm * rs + bm, in-place in `at` stripe-wise.
#pragma unroll
    for (int rt = 0; rt < 4; ++rt) {
        s16x8 af[4];
#pragma unroll
        for (int kb = 0; kb < 4; ++kb)
            af[kb] = read_frag(at, rt * 16 + lr, kb * 32 + 8 * lg);
        __syncthreads();
        const int rbase = r0 + rt * 16 + 4 * lg;
        float rs[4];
#pragma unroll
        for (int j = 0; j < 4; ++j)
            rs[j] = (rbase + j < N) ? 1.0f / fmaxf((float)deg[rbase + j], 1e-8f) : 0.f;
#pragma unroll
        for (int ct = 0; ct < 2; ++ct) {
            f32x4 acc = {0.f, 0.f, 0.f, 0.f};
#pragma unroll
            for (int kb = 0; kb < 4; ++kb)
                acc = __builtin_amdgcn_mfma_f32_16x16x32_bf16(af[kb], B1[ct][kb], acc, 0, 0, 0);
            const float bb = ct ? bm1 : bm0;
            const int col = ct ? col1 : col0;
#pragma unroll
            for (int j = 0; j < 4; ++j)
                *(ushort*)(at + swz(rt * 16 + 4 * lg + j, col)) = f2b(acc[j] * rs[j] + bb);
        }
    }
    __syncthreads();

    // Stage 2
    float v[4][2][4];
#pragma unroll
    for (int rt = 0; rt < 4; ++rt) {
        s16x8 af[4];
#pragma unroll
        for (int kb = 0; kb < 4; ++kb)
            af[kb] = read_frag(at, rt * 16 + lr, kb * 32 + 8 * lg);
        const int rbase = r0 + rt * 16 + 4 * lg;
#pragma unroll
        for (int ct = 0; ct < 2; ++ct) {
            f32x4 acc = {0.f, 0.f, 0.f, 0.f};
#pragma unroll
            for (int kb = 0; kb < 4; ++kb)
                acc = __builtin_amdgcn_mfma_f32_16x16x32_bf16(af[kb], B2[ct][kb], acc, 0, 0, 0);
            const int col = ct ? col1 : col0;
            const float bgc = ct ? bg1 : bg0;
#pragma unroll
            for (int j = 0; j < 4; ++j) {
                const float rv = (rbase + j < N) ? resid[(size_t)(rbase + j) * 128 + col] : 0.f;
                v[rt][ct][j] = acc[j] + bgc + rv;
            }
        }
    }
#pragma unroll
    for (int rt = 0; rt < 4; ++rt)
#pragma unroll
        for (int j = 0; j < 4; ++j) {
            float s = v[rt][0][j] + v[rt][1][j];
            float q = v[rt][0][j] * v[rt][0][j] + v[rt][1][j] * v[rt][1][j];
            s += __shfl_xor(s, 8); q += __shfl_xor(q, 8);
            s += __shfl_xor(s, 4); q += __shfl_xor(q, 4);
            s += __shfl_xor(s, 2); q += __shfl_xor(q, 2);
            s += __shfl_xor(s, 1); q += __shfl_xor(q, 1);
            if (lr == 0) part[w][rt * 16 + 4 * lg + j] = make_float2(s, q);
        }
    __syncthreads();
    if (t < 64) {
        const float S = part[0][t].x + part[1][t].x + part[2][t].x + part[3][t].x;
        const float Qq = part[0][t].y + part[1][t].y + part[2][t].y + part[3][t].y;
        const float mu = S * (1.f / 128.f);
        const float var = Qq * (1.f / 128.f) - mu * mu;
        lnp[t] = make_float2(mu, rsqrtf(var + 1e-5f));
    }
    __syncthreads();
#pragma unroll
    for (int rt = 0; rt < 4; ++rt) {
        const int rbase = r0 + rt * 16 + 4 * lg;
#pragma unroll
        for (int j = 0; j < 4; ++j) {
            const float2 mp = lnp[rt * 16 + 4 * lg + j];
            if (rbase + j < N) {
                out[(size_t)(rbase + j) * 128 + col0] = (v[rt][0][j] - mp.x) * mp.y * g0 + be0;
                out[(size_t)(rbase + j) * 128 + col1] = (v[rt][1][j] - mp.x) * mp.y * g1 + be1;
            }
        }
    }
}

// ---------------------------------------------------------------------------
// post2: [0,nti) item tiles | [nti,nti+ntu) user tiles
// ---------------------------------------------------------------------------
__global__ __launch_bounds__(256) void post2_kernel(
    const ushort* __restrict__ msgA, const int* __restrict__ cnt_i,
    const float* __restrict__ Wmi, const float* __restrict__ bmi,
    const float* __restrict__ Wgi, const float* __restrict__ bgi,
    const float* __restrict__ xi, const float* __restrict__ lngi, const float* __restrict__ lnbi,
    float* __restrict__ out_item, int n_item, int nti,
    const ushort* __restrict__ msgB, const int* __restrict__ cnt_u,
    const float* __restrict__ Wmu, const float* __restrict__ bmu,
    const float* __restrict__ Wgu, const float* __restrict__ bgu,
    const float* __restrict__ xu, const float* __restrict__ lngu, const float* __restrict__ lnbu,
    float* __restrict__ out_user, int n_user)
{
    __shared__ char wt[32768];
    __shared__ char at[16384];
    __shared__ float2 part[4][64];
    __shared__ float2 lnp[64];
    const int b = blockIdx.x;
    if (b < nti) {
        post_body(msgA, cnt_i, Wmi, bmi, Wgi, bgi, xi, lngi, lnbi, out_item, n_item, b,
                  wt, at, part, lnp);
    } else {
        post_body(msgB, cnt_u, Wmu, bmu, Wgu, bgu, xu, lngu, lnbu, out_user, n_user, b - nti,
                  wt, at, part, lnp);
    }
}

// ---------------------------------------------------------------------------
extern "C" void kernel_launch(void* const* d_in, const int* in_sizes, int n_in,
                              void* d_out, int out_size, void* d_ws, size_t ws_size,
                              hipStream_t stream)
{
    const float* x_user  = (const float*)d_in[0];
    const float* x_item  = (const float*)d_in[1];
    const int*   ei_ui   = (const int*)d_in[2];
    const int*   ei_iu   = (const int*)d_in[3];
    const float* Wk_user = (const float*)d_in[4];
    const float* Wq_user = (const float*)d_in[5];
    const float* Wv_user = (const float*)d_in[6];
    const float* Wk_item = (const float*)d_in[7];
    const float* Wq_item = (const float*)d_in[8];
    const float* Wv_item = (const float*)d_in[9];
    const float* Wa_ui   = (const float*)d_in[10];
    const float* Wa_iu   = (const float*)d_in[11];
    const float* Wm_user = (const float*)d_in[12];
    const float* bm_user = (const float*)d_in[13];
    const float* Wm_item = (const float*)d_in[14];
    const float* bm_item = (const float*)d_in[15];
    const float* Wg_user = (const float*)d_in[16];
    const float* bg_user = (const float*)d_in[17];
    const float* Wg_item = (const float*)d_in[18];
    const float* bg_item = (const float*)d_in[19];
    const float* lng_user = (const float*)d_in[20];
    const float* lnb_user = (const float*)d_in[21];
    const float* lng_item = (const float*)d_in[22];
    const float* lnb_item = (const float*)d_in[23];

    const int n_user = in_sizes[0] / DIM;
    const int n_item = in_sizes[1] / DIM;
    const int E = in_sizes[2] / 2;
    const int nmax = (n_user > n_item) ? n_user : n_item;
    const int ntot = n_user + n_item;
    const size_t nf = (size_t)nmax * DIM;

    ushort* Ku   = (ushort*)d_ws;
    ushort* Qu   = Ku + nf;
    ushort* Vu   = Qu + nf;
    ushort* Ki   = Vu + nf;
    ushort* Qi   = Ki + nf;
    ushort* Vi   = Qi + nf;
    ushort* msgA = Vi + nf;
    ushort* msgB = msgA + nf;
    float* kwa_u = (float*)(msgB + nf);
    float* kwa_i = kwa_u + (size_t)nmax * 4;
    int* cnt     = (int*)(kwa_i + (size_t)nmax * 4);  // [ntot] items then users
    int* cursor  = cnt + ntot;                        // [4]
    int* basep   = cursor + 4;                        // [ntot]
    int* fill    = basep + ntot;                      // [ntot]
    int* bucket  = fill + ntot;                       // [2E]

    float* out_user = (float*)d_out;
    float* out_item = out_user + (size_t)n_user * DIM;

    const dim3 blk(256);
    const int ntu = (n_user + 63) / 64, nti = (n_item + 63) / 64;
    const int histB = (2 * E + 255) / 256;

    hipMemsetAsync(cnt, 0, ((size_t)ntot + 4) * sizeof(int), stream);

    // proj_user || proj_item || hist  (independent work, one launch)
    fused_proj_hist<<<ntu + nti + histB, blk, 0, stream>>>(
        x_user, Wk_user, Wq_user, Wv_user, Wa_ui, Ku, Qu, Vu, kwa_u, n_user, ntu,
        x_item, Wk_item, Wq_item, Wv_item, Wa_iu, Ki, Qi, Vi, kwa_i, n_item, nti,
        ei_ui + E, ei_iu + E, cnt, E);

    alloc_kernel<<<(ntot + 255) / 256, blk, 0, stream>>>(cnt, basep, fill, cursor, ntot);
    scatter_kernel<<<histB, blk, 0, stream>>>(ei_ui, ei_iu, fill, bucket, n_item, E);

    // agg over concatenated dst space (items then users)
    agg2_kernel<<<(ntot + 3) / 4, blk, 0, stream>>>(
        basep, cnt, bucket,
        Ku, Qi, Vu, kwa_u, msgA,
        Ki, Qu, Vi, kwa_i, msgB,
        n_item, ntot);

    // post_item || post_user
    post2_kernel<<<nti + ntu, blk, 0, stream>>>(
        msgA, cnt, Wm_item, bm_item, Wg_item, bg_item, x_item, lng_item, lnb_item, out_item, n_item, nti,
        msgB, cnt + n_item, Wm_user, bm_user, Wg_user, bg_user, x_user, lng_user, lnb_user, out_user, n_user);
}

// Round 6
// 338.890 us; speedup vs baseline: 1.0762x; 1.0762x over previous
//
#include <hip/hip_runtime.h>
#include <hip/hip_bf16.h>

#define DIM 128

typedef short s16x8 __attribute__((ext_vector_type(8)));
typedef float f32x4 __attribute__((ext_vector_type(4)));

__device__ __forceinline__ ushort f2b(float f) {
    __hip_bfloat16 h = __float2bfloat16(f);
    return *reinterpret_cast<ushort*>(&h);
}
__device__ __forceinline__ uint pk2(float a, float b) {
    return (uint)f2b(a) | ((uint)f2b(b) << 16);
}
__device__ __forceinline__ float bl(uint u) { return __uint_as_float(u << 16); }
__device__ __forceinline__ float bh(uint u) { return __uint_as_float(u & 0xffff0000u); }

// Swizzled byte address inside a [rows][128 bf16] LDS tile (256B rows).
__device__ __forceinline__ int swz(int row, int kelem) {
    int b = row * 256 + kelem * 2;
    return b ^ ((row & 7) << 4);
}
__device__ __forceinline__ s16x8 read_frag(const char* lds, int row, int k0) {
    return *(const s16x8*)(lds + swz(row, k0));
}

// Load one B-operand fragment set straight from global W (fp32, row-major
// [k][n]) with bf16 packing. Weights are L2-resident; no LDS staging.
__device__ __forceinline__ void load_bfrag(const float* __restrict__ W,
                                           s16x8 B[2][4], int w, int lr, int lg) {
#pragma unroll
    for (int ct = 0; ct < 2; ++ct) {
        const float* p = W + (w * 32 + ct * 16 + lr);
#pragma unroll
        for (int kb = 0; kb < 4; ++kb) {
            const int k0 = kb * 32 + 8 * lg;
            uint4 u;
            u.x = pk2(p[(size_t)(k0 + 0) * 128], p[(size_t)(k0 + 1) * 128]);
            u.y = pk2(p[(size_t)(k0 + 2) * 128], p[(size_t)(k0 + 3) * 128]);
            u.z = pk2(p[(size_t)(k0 + 4) * 128], p[(size_t)(k0 + 5) * 128]);
            u.w = pk2(p[(size_t)(k0 + 6) * 128], p[(size_t)(k0 + 7) * 128]);
            B[ct][kb] = *(s16x8*)&u;
        }
    }
}

__device__ __forceinline__ void stage_f32(const float* __restrict__ src, int r0, int N, char* lds) {
    const int t = threadIdx.x;
    const int r = t >> 2;
    const int k0 = (t & 3) * 32;
    const int row = r0 + r;
#pragma unroll
    for (int c = 0; c < 4; ++c) {
        uint4 u = make_uint4(0, 0, 0, 0);
        if (row < N) {
            const float4 f0 = *(const float4*)&src[(size_t)row * 128 + k0 + c * 8];
            const float4 f1 = *(const float4*)&src[(size_t)row * 128 + k0 + c * 8 + 4];
            u.x = pk2(f0.x, f0.y); u.y = pk2(f0.z, f0.w);
            u.z = pk2(f1.x, f1.y); u.w = pk2(f1.z, f1.w);
        }
        *(uint4*)(lds + swz(r, k0 + c * 8)) = u;
    }
}

__device__ __forceinline__ void stage_b16(const ushort* __restrict__ src, int r0, int N, char* lds) {
    const int t = threadIdx.x;
    const int r = t >> 2;
    const int k0 = (t & 3) * 32;
    const int row = r0 + r;
#pragma unroll
    for (int c = 0; c < 4; ++c) {
        uint4 u = make_uint4(0, 0, 0, 0);
        if (row < N) u = *(const uint4*)&src[(size_t)row * 128 + k0 + c * 8];
        *(uint4*)(lds + swz(r, k0 + c * 8)) = u;
    }
}

// ---------------------------------------------------------------------------
// proj body: one 64-row tile. K (+fused kwa), Q, V processed sequentially so
// only one weight-matrix fragment set (16 VGPR) is live at a time.
// LDS: at 16KB + kwp 4KB = 20KB.
// ---------------------------------------------------------------------------
__device__ void proj_body(
    const float* __restrict__ x,
    const float* __restrict__ Wk, const float* __restrict__ Wq, const float* __restrict__ Wv,
    const float* __restrict__ Wa,
    ushort* __restrict__ K, ushort* __restrict__ Q, ushort* __restrict__ V,
    float* __restrict__ kwa, int N, int tile, char* mem)
{
    const int t = threadIdx.x, w = t >> 6, l = t & 63;
    const int lr = l & 15, lg = l >> 4;
    char* at = mem;                                        // 16KB A-tile
    float (*kwp)[64][4] = (float (*)[64][4])(mem + 16384); // 4KB partials

    const int r0 = tile << 6;
    stage_f32(x, r0, N, at);
    __syncthreads();

    const int col0 = w * 32 + lr, col1 = col0 + 16;

    // ---- K + fused kwa ----
    {
        s16x8 B[2][4];
        load_bfrag(Wk, B, w, lr, lg);
        const float4 waA = *(const float4*)&Wa[col0 * 4];
        const float4 waB = *(const float4*)&Wa[col1 * 4];
#pragma unroll
        for (int rt = 0; rt < 4; ++rt) {
            s16x8 af[4];
#pragma unroll
            for (int kb = 0; kb < 4; ++kb)
                af[kb] = read_frag(at, rt * 16 + lr, kb * 32 + 8 * lg);
            const int rbase = r0 + rt * 16 + 4 * lg;
            f32x4 a0 = {0.f, 0.f, 0.f, 0.f}, a1 = {0.f, 0.f, 0.f, 0.f};
#pragma unroll
            for (int kb = 0; kb < 4; ++kb) {
                a0 = __builtin_amdgcn_mfma_f32_16x16x32_bf16(af[kb], B[0][kb], a0, 0, 0, 0);
                a1 = __builtin_amdgcn_mfma_f32_16x16x32_bf16(af[kb], B[1][kb], a1, 0, 0, 0);
            }
#pragma unroll
            for (int j = 0; j < 4; ++j) {
                if (rbase + j < N) {
                    K[(size_t)(rbase + j) * 128 + col0] = f2b(a0[j]);
                    K[(size_t)(rbase + j) * 128 + col1] = f2b(a1[j]);
                }
            }
#pragma unroll
            for (int j = 0; j < 4; ++j) {
                float p0 = a0[j] * waA.x + a1[j] * waB.x;
                float p1 = a0[j] * waA.y + a1[j] * waB.y;
                float p2 = a0[j] * waA.z + a1[j] * waB.z;
                float p3 = a0[j] * waA.w + a1[j] * waB.w;
#pragma unroll
                for (int off = 8; off; off >>= 1) {
                    p0 += __shfl_xor(p0, off);
                    p1 += __shfl_xor(p1, off);
                    p2 += __shfl_xor(p2, off);
                    p3 += __shfl_xor(p3, off);
                }
                if (lr == 0) {
                    kwp[w][rt * 16 + 4 * lg + j][0] = p0;
                    kwp[w][rt * 16 + 4 * lg + j][1] = p1;
                    kwp[w][rt * 16 + 4 * lg + j][2] = p2;
                    kwp[w][rt * 16 + 4 * lg + j][3] = p3;
                }
            }
        }
    }
    __syncthreads();
    if (t < 64 && r0 + t < N) {
        const float s0 = kwp[0][t][0] + kwp[1][t][0] + kwp[2][t][0] + kwp[3][t][0];
        const float s1 = kwp[0][t][1] + kwp[1][t][1] + kwp[2][t][1] + kwp[3][t][1];
        const float s2 = kwp[0][t][2] + kwp[1][t][2] + kwp[2][t][2] + kwp[3][t][2];
        const float s3 = kwp[0][t][3] + kwp[1][t][3] + kwp[2][t][3] + kwp[3][t][3];
        *(float4*)&kwa[(size_t)(r0 + t) * 4] = make_float4(s0, s1, s2, s3);
    }

    // ---- Q then V (no kwa) ----
    const float* Ws[2] = {Wq, Wv};
    ushort* Os[2] = {Q, V};
#pragma unroll
    for (int m = 0; m < 2; ++m) {
        s16x8 B[2][4];
        load_bfrag(Ws[m], B, w, lr, lg);
        ushort* O = Os[m];
#pragma unroll
        for (int rt = 0; rt < 4; ++rt) {
            s16x8 af[4];
#pragma unroll
            for (int kb = 0; kb < 4; ++kb)
                af[kb] = read_frag(at, rt * 16 + lr, kb * 32 + 8 * lg);
            const int rbase = r0 + rt * 16 + 4 * lg;
            f32x4 a0 = {0.f, 0.f, 0.f, 0.f}, a1 = {0.f, 0.f, 0.f, 0.f};
#pragma unroll
            for (int kb = 0; kb < 4; ++kb) {
                a0 = __builtin_amdgcn_mfma_f32_16x16x32_bf16(af[kb], B[0][kb], a0, 0, 0, 0);
                a1 = __builtin_amdgcn_mfma_f32_16x16x32_bf16(af[kb], B[1][kb], a1, 0, 0, 0);
            }
#pragma unroll
            for (int j = 0; j < 4; ++j) {
                if (rbase + j < N) {
                    O[(size_t)(rbase + j) * 128 + col0] = f2b(a0[j]);
                    O[(size_t)(rbase + j) * 128 + col1] = f2b(a1[j]);
                }
            }
        }
    }
}

// ---------------------------------------------------------------------------
// proj_both: [0,ntu) user tiles | [ntu,ntu+nti) item tiles. Same footprint.
// ---------------------------------------------------------------------------
__global__ __launch_bounds__(256) void proj_both(
    const float* __restrict__ xu,
    const float* __restrict__ Wku, const float* __restrict__ Wqu, const float* __restrict__ Wvu,
    const float* __restrict__ Waui,
    ushort* __restrict__ Ku, ushort* __restrict__ Qu, ushort* __restrict__ Vu,
    float* __restrict__ kwa_u, int n_user, int ntu,
    const float* __restrict__ xi,
    const float* __restrict__ Wki, const float* __restrict__ Wqi, const float* __restrict__ Wvi,
    const float* __restrict__ Waiu,
    ushort* __restrict__ Ki, ushort* __restrict__ Qi, ushort* __restrict__ Vi,
    float* __restrict__ kwa_i, int n_item)
{
    __shared__ char mem[20480];
    const int b = blockIdx.x;
    if (b < ntu)
        proj_body(xu, Wku, Wqu, Wvu, Waui, Ku, Qu, Vu, kwa_u, n_user, b, mem);
    else
        proj_body(xi, Wki, Wqi, Wvi, Waiu, Ki, Qi, Vi, kwa_i, n_item, b - ntu, mem);
}

// ---------------------------------------------------------------------------
__global__ __launch_bounds__(256) void hist_kernel(
    const int* __restrict__ dst_i, const int* __restrict__ dst_u,
    int* __restrict__ cnt, int ni, int E)
{
    const int e = blockIdx.x * blockDim.x + threadIdx.x;
    if (e < E) atomicAdd(&cnt[dst_i[e]], 1);
    else if (e < 2 * E) atomicAdd(&cnt[ni + dst_u[e - E]], 1);
}

__global__ __launch_bounds__(256) void alloc_kernel(
    const int* __restrict__ cnt, int* __restrict__ base,
    int* __restrict__ fill, int* __restrict__ cursor, int n)
{
    const int d = blockIdx.x * blockDim.x + threadIdx.x;
    const int lane = threadIdx.x & 63;
    int c = (d < n) ? cnt[d] : 0;
    int sc = c;
#pragma unroll
    for (int off = 1; off < 64; off <<= 1) {
        int t = __shfl_up(sc, off);
        if (lane >= off) sc += t;
    }
    const int total = __shfl(sc, 63);
    int wb = 0;
    if (lane == 63) wb = atomicAdd(cursor, total);
    wb = __shfl(wb, 63);
    if (d < n) {
        const int b = wb + sc - c;
        base[d] = b;
        fill[d] = b;
    }
}

template<typename IT>
__global__ __launch_bounds__(256) void scatter_kernel(
    const int* __restrict__ ei_ui, const int* __restrict__ ei_iu,
    int* __restrict__ fill, IT* __restrict__ bucket, int ni, int E)
{
    const int e = blockIdx.x * blockDim.x + threadIdx.x;
    if (e < E) {
        const int pos = atomicAdd(&fill[ei_ui[E + e]], 1);
        bucket[pos] = (IT)ei_ui[e];
    } else if (e < 2 * E) {
        const int pos = atomicAdd(&fill[ni + ei_iu[E + e - E]], 1);
        bucket[pos] = (IT)ei_iu[e - E];
    }
}

// ---------------------------------------------------------------------------
// agg2: one wave per dst over the concatenated dst space. 4-wide unroll.
// ---------------------------------------------------------------------------
template<typename IT>
__global__ __launch_bounds__(256) void agg2_kernel(
    const int* __restrict__ base, const int* __restrict__ cnt, const IT* __restrict__ bsrc,
    const ushort* __restrict__ Ku, const ushort* __restrict__ Qi, const ushort* __restrict__ Vu,
    const float* __restrict__ kwa_u, ushort* __restrict__ msgA,
    const ushort* __restrict__ Ki, const ushort* __restrict__ Qu, const ushort* __restrict__ Vi,
    const float* __restrict__ kwa_i, ushort* __restrict__ msgB,
    int n_item, int ntot)
{
    const int widx = (int)((blockIdx.x * blockDim.x + threadIdx.x) >> 6);
    if (widx >= ntot) return;
    const bool item_side = widx < n_item;
    const int d = item_side ? widx : widx - n_item;
    const ushort* K  = item_side ? Ku : Ki;
    const ushort* Q  = item_side ? Qi : Qu;
    const ushort* V  = item_side ? Vu : Vi;
    const float* kwa = item_side ? kwa_u : kwa_i;
    ushort* msg      = item_side ? msgA : msgB;

    const int l = threadIdx.x & 63;
    const int h = l >> 4;
    const float inv = 0.17677669529663687f;   // 1/sqrt(32)
    const uint qu = *(const uint*)&Q[(size_t)d * 128 + 2 * l];
    const float qx = bl(qu), qy = bh(qu);
    const int b = base[widx], c = cnt[widx];
    float mx = 0.f, my = 0.f;

    for (int i = 0; i < c; i += 4) {
        const int s0 = (int)bsrc[b + i];
        const int s1 = (i + 1 < c) ? (int)bsrc[b + i + 1] : s0;
        const int s2 = (i + 2 < c) ? (int)bsrc[b + i + 2] : s0;
        const int s3 = (i + 3 < c) ? (int)bsrc[b + i + 3] : s0;

        const uint ku0 = *(const uint*)&K[(size_t)s0 * 128 + 2 * l];
        const uint ku1 = *(const uint*)&K[(size_t)s1 * 128 + 2 * l];
        const uint ku2 = *(const uint*)&K[(size_t)s2 * 128 + 2 * l];
        const uint ku3 = *(const uint*)&K[(size_t)s3 * 128 + 2 * l];
        const uint vu0 = *(const uint*)&V[(size_t)s0 * 128 + 2 * l];
        const uint vu1 = *(const uint*)&V[(size_t)s1 * 128 + 2 * l];
        const uint vu2 = *(const uint*)&V[(size_t)s2 * 128 + 2 * l];
        const uint vu3 = *(const uint*)&V[(size_t)s3 * 128 + 2 * l];
        const float kw0 = kwa[(size_t)s0 * 4 + h];
        const float kw1 = kwa[(size_t)s1 * 4 + h];
        const float kw2 = kwa[(size_t)s2 * 4 + h];
        const float kw3 = kwa[(size_t)s3 * 4 + h];

        float p0 = bl(ku0) * qx + bh(ku0) * qy;
        float p1 = bl(ku1) * qx + bh(ku1) * qy;
        float p2 = bl(ku2) * qx + bh(ku2) * qy;
        float p3 = bl(ku3) * qx + bh(ku3) * qy;
#pragma unroll
        for (int off = 8; off; off >>= 1) {
            p0 += __shfl_xor(p0, off);
            p1 += __shfl_xor(p1, off);
            p2 += __shfl_xor(p2, off);
            p3 += __shfl_xor(p3, off);
        }
        const float e0 = __expf(p0 * inv + kw0);
        const float e1 = __expf(p1 * inv + kw1);
        const float e2 = __expf(p2 * inv + kw2);
        const float e3 = __expf(p3 * inv + kw3);
        float es0 = e0 + __shfl_xor(e0, 16);
        float es1 = e1 + __shfl_xor(e1, 16);
        float es2 = e2 + __shfl_xor(e2, 16);
        float es3 = e3 + __shfl_xor(e3, 16);
        es0 += __shfl_xor(es0, 32);
        es1 += __shfl_xor(es1, 32);
        es2 += __shfl_xor(es2, 32);
        es3 += __shfl_xor(es3, 32);
        const float a0 = __fdividef(e0, es0);
        const float a1 = (i + 1 < c) ? __fdividef(e1, es1) : 0.f;
        const float a2 = (i + 2 < c) ? __fdividef(e2, es2) : 0.f;
        const float a3 = (i + 3 < c) ? __fdividef(e3, es3) : 0.f;

        mx += a0 * bl(vu0) + a1 * bl(vu1) + a2 * bl(vu2) + a3 * bl(vu3);
        my += a0 * bh(vu0) + a1 * bh(vu1) + a2 * bh(vu2) + a3 * bh(vu3);
    }
    *(uint*)&msg[(size_t)d * 128 + 2 * l] = pk2(mx, my);
}

// ---------------------------------------------------------------------------
// post body: one 64-row tile of LN(((A@Wm)*rs+bm)@Wg + bg + resid)*g + b.
// Weight frags loaded from global per stage. LDS: at 16KB + part 2KB + lnp.
// ---------------------------------------------------------------------------
__device__ void post_body(
    const ushort* __restrict__ A, const int* __restrict__ deg,
    const float* __restrict__ Wm, const float* __restrict__ bm,
    const float* __restrict__ Wg, const float* __restrict__ bg,
    const float* __restrict__ resid, const float* __restrict__ gamma,
    const float* __restrict__ beta, float* __restrict__ out, int N, int tile, char* mem)
{
    const int t = threadIdx.x, w = t >> 6, l = t & 63;
    const int lr = l & 15, lg = l >> 4;
    char* at = mem;                                    // 16KB
    float2 (*part)[64] = (float2 (*)[64])(mem + 16384); // 2KB
    float2* lnp = (float2*)(mem + 16384 + 2048);        // 512B

    const int col0 = w * 32 + lr, col1 = col0 + 16;
    const int r0 = tile << 6;
    stage_b16(A, r0, N, at);
    __syncthreads();

    // Stage 1: tmp = A@Wm * rs + bm, in-place in `at` stripe-wise.
    {
        s16x8 B[2][4];
        load_bfrag(Wm, B, w, lr, lg);
        const float bm0 = bm[col0], bm1 = bm[col1];
#pragma unroll
        for (int rt = 0; rt < 4; ++rt) {
            s16x8 af[4];
#pragma unroll
            for (int kb = 0; kb < 4; ++kb)
                af[kb] = read_frag(at, rt * 16 + lr, kb * 32 + 8 * lg);
            __syncthreads();   // all waves read stripe rt before overwrite
            const int rbase = r0 + rt * 16 + 4 * lg;
            float rs[4];
#pragma unroll
            for (int j = 0; j < 4; ++j)
                rs[j] = (rbase + j < N) ? 1.0f / fmaxf((float)deg[rbase + j], 1e-8f) : 0.f;
            f32x4 a0 = {0.f, 0.f, 0.f, 0.f}, a1 = {0.f, 0.f, 0.f, 0.f};
#pragma unroll
            for (int kb = 0; kb < 4; ++kb) {
                a0 = __builtin_amdgcn_mfma_f32_16x16x32_bf16(af[kb], B[0][kb], a0, 0, 0, 0);
                a1 = __builtin_amdgcn_mfma_f32_16x16x32_bf16(af[kb], B[1][kb], a1, 0, 0, 0);
            }
#pragma unroll
            for (int j = 0; j < 4; ++j) {
                *(ushort*)(at + swz(rt * 16 + 4 * lg + j, col0)) = f2b(a0[j] * rs[j] + bm0);
                *(ushort*)(at + swz(rt * 16 + 4 * lg + j, col1)) = f2b(a1[j] * rs[j] + bm1);
            }
        }
    }
    __syncthreads();

    // Stage 2: v = tmp@Wg + bg + resid, then LayerNorm.
    float v[4][2][4];
    {
        s16x8 B[2][4];
        load_bfrag(Wg, B, w, lr, lg);
        const float bg0 = bg[col0], bg1 = bg[col1];
#pragma unroll
        for (int rt = 0; rt < 4; ++rt) {
            s16x8 af[4];
#pragma unroll
            for (int kb = 0; kb < 4; ++kb)
                af[kb] = read_frag(at, rt * 16 + lr, kb * 32 + 8 * lg);
            const int rbase = r0 + rt * 16 + 4 * lg;
            f32x4 a0 = {0.f, 0.f, 0.f, 0.f}, a1 = {0.f, 0.f, 0.f, 0.f};
#pragma unroll
            for (int kb = 0; kb < 4; ++kb) {
                a0 = __builtin_amdgcn_mfma_f32_16x16x32_bf16(af[kb], B[0][kb], a0, 0, 0, 0);
                a1 = __builtin_amdgcn_mfma_f32_16x16x32_bf16(af[kb], B[1][kb], a1, 0, 0, 0);
            }
#pragma unroll
            for (int j = 0; j < 4; ++j) {
                const bool ok = (rbase + j < N);
                const float rv0 = ok ? resid[(size_t)(rbase + j) * 128 + col0] : 0.f;
                const float rv1 = ok ? resid[(size_t)(rbase + j) * 128 + col1] : 0.f;
                v[rt][0][j] = a0[j] + bg0 + rv0;
                v[rt][1][j] = a1[j] + bg1 + rv1;
            }
        }
    }
#pragma unroll
    for (int rt = 0; rt < 4; ++rt)
#pragma unroll
        for (int j = 0; j < 4; ++j) {
            float s = v[rt][0][j] + v[rt][1][j];
            float q = v[rt][0][j] * v[rt][0][j] + v[rt][1][j] * v[rt][1][j];
            s += __shfl_xor(s, 8); q += __shfl_xor(q, 8);
            s += __shfl_xor(s, 4); q += __shfl_xor(q, 4);
            s += __shfl_xor(s, 2); q += __shfl_xor(q, 2);
            s += __shfl_xor(s, 1); q += __shfl_xor(q, 1);
            if (lr == 0) part[w][rt * 16 + 4 * lg + j] = make_float2(s, q);
        }
    __syncthreads();
    if (t < 64) {
        const float S = part[0][t].x + part[1][t].x + part[2][t].x + part[3][t].x;
        const float Qq = part[0][t].y + part[1][t].y + part[2][t].y + part[3][t].y;
        const float mu = S * (1.f / 128.f);
        const float var = Qq * (1.f / 128.f) - mu * mu;
        lnp[t] = make_float2(mu, rsqrtf(var + 1e-5f));
    }
    __syncthreads();
    const float g0 = gamma[col0], g1 = gamma[col1];
    const float be0 = beta[col0], be1 = beta[col1];
#pragma unroll
    for (int rt = 0; rt < 4; ++rt) {
        const int rbase = r0 + rt * 16 + 4 * lg;
#pragma unroll
        for (int j = 0; j < 4; ++j) {
            const float2 mp = lnp[rt * 16 + 4 * lg + j];
            if (rbase + j < N) {
                out[(size_t)(rbase + j) * 128 + col0] = (v[rt][0][j] - mp.x) * mp.y * g0 + be0;
                out[(size_t)(rbase + j) * 128 + col1] = (v[rt][1][j] - mp.x) * mp.y * g1 + be1;
            }
        }
    }
}

__global__ __launch_bounds__(256) void post2_kernel(
    const ushort* __restrict__ msgA, const int* __restrict__ cnt_i,
    const float* __restrict__ Wmi, const float* __restrict__ bmi,
    const float* __restrict__ Wgi, const float* __restrict__ bgi,
    const float* __restrict__ xi, const float* __restrict__ lngi, const float* __restrict__ lnbi,
    float* __restrict__ out_item, int n_item, int nti,
    const ushort* __restrict__ msgB, const int* __restrict__ cnt_u,
    const float* __restrict__ Wmu, const float* __restrict__ bmu,
    const float* __restrict__ Wgu, const float* __restrict__ bgu,
    const float* __restrict__ xu, const float* __restrict__ lngu, const float* __restrict__ lnbu,
    float* __restrict__ out_user, int n_user)
{
    __shared__ char mem[16384 + 2048 + 512];
    const int b = blockIdx.x;
    if (b < nti)
        post_body(msgA, cnt_i, Wmi, bmi, Wgi, bgi, xi, lngi, lnbi, out_item, n_item, b, mem);
    else
        post_body(msgB, cnt_u, Wmu, bmu, Wgu, bgu, xu, lngu, lnbu, out_user, n_user, b - nti, mem);
}

// ---------------------------------------------------------------------------
extern "C" void kernel_launch(void* const* d_in, const int* in_sizes, int n_in,
                              void* d_out, int out_size, void* d_ws, size_t ws_size,
                              hipStream_t stream)
{
    const float* x_user  = (const float*)d_in[0];
    const float* x_item  = (const float*)d_in[1];
    const int*   ei_ui   = (const int*)d_in[2];
    const int*   ei_iu   = (const int*)d_in[3];
    const float* Wk_user = (const float*)d_in[4];
    const float* Wq_user = (const float*)d_in[5];
    const float* Wv_user = (const float*)d_in[6];
    const float* Wk_item = (const float*)d_in[7];
    const float* Wq_item = (const float*)d_in[8];
    const float* Wv_item = (const float*)d_in[9];
    const float* Wa_ui   = (const float*)d_in[10];
    const float* Wa_iu   = (const float*)d_in[11];
    const float* Wm_user = (const float*)d_in[12];
    const float* bm_user = (const float*)d_in[13];
    const float* Wm_item = (const float*)d_in[14];
    const float* bm_item = (const float*)d_in[15];
    const float* Wg_user = (const float*)d_in[16];
    const float* bg_user = (const float*)d_in[17];
    const float* Wg_item = (const float*)d_in[18];
    const float* bg_item = (const float*)d_in[19];
    const float* lng_user = (const float*)d_in[20];
    const float* lnb_user = (const float*)d_in[21];
    const float* lng_item = (const float*)d_in[22];
    const float* lnb_item = (const float*)d_in[23];

    const int n_user = in_sizes[0] / DIM;
    const int n_item = in_sizes[1] / DIM;
    const int E = in_sizes[2] / 2;
    const int nmax = (n_user > n_item) ? n_user : n_item;
    const int ntot = n_user + n_item;
    const size_t nf = (size_t)nmax * DIM;

    ushort* Ku   = (ushort*)d_ws;
    ushort* Qu   = Ku + nf;
    ushort* Vu   = Qu + nf;
    ushort* Ki   = Vu + nf;
    ushort* Qi   = Ki + nf;
    ushort* Vi   = Qi + nf;
    ushort* msgA = Vi + nf;
    ushort* msgB = msgA + nf;
    float* kwa_u = (float*)(msgB + nf);
    float* kwa_i = kwa_u + (size_t)nmax * 4;
    int* cnt     = (int*)(kwa_i + (size_t)nmax * 4);  // [ntot] items then users
    int* cursor  = cnt + ntot;                        // [4]
    int* basep   = cursor + 4;                        // [ntot]
    int* fill    = basep + ntot;                      // [ntot]
    void* bucket = (void*)(fill + ntot);              // [2E] u16 or u32

    float* out_user = (float*)d_out;
    float* out_item = out_user + (size_t)n_user * DIM;

    const dim3 blk(256);
    const int ntu = (n_user + 63) / 64, nti = (n_item + 63) / 64;
    const int histB = (2 * E + 255) / 256;

    hipMemsetAsync(cnt, 0, ((size_t)ntot + 4) * sizeof(int), stream);

    proj_both<<<ntu + nti, blk, 0, stream>>>(
        x_user, Wk_user, Wq_user, Wv_user, Wa_ui, Ku, Qu, Vu, kwa_u, n_user, ntu,
        x_item, Wk_item, Wq_item, Wv_item, Wa_iu, Ki, Qi, Vi, kwa_i, n_item);

    hist_kernel<<<histB, blk, 0, stream>>>(ei_ui + E, ei_iu + E, cnt, n_item, E);
    alloc_kernel<<<(ntot + 255) / 256, blk, 0, stream>>>(cnt, basep, fill, cursor, ntot);

    if (nmax <= 65535) {
        scatter_kernel<ushort><<<histB, blk, 0, stream>>>(ei_ui, ei_iu, fill, (ushort*)bucket, n_item, E);
        agg2_kernel<ushort><<<(ntot + 3) / 4, blk, 0, stream>>>(
            basep, cnt, (const ushort*)bucket,
            Ku, Qi, Vu, kwa_u, msgA,
            Ki, Qu, Vi, kwa_i, msgB,
            n_item, ntot);
    } else {
        scatter_kernel<int><<<histB, blk, 0, stream>>>(ei_ui, ei_iu, fill, (int*)bucket, n_item, E);
        agg2_kernel<int><<<(ntot + 3) / 4, blk, 0, stream>>>(
            basep, cnt, (const int*)bucket,
            Ku, Qi, Vu, kwa_u, msgA,
            Ki, Qu, Vi, kwa_i, msgB,
            n_item, ntot);
    }

    post2_kernel<<<nti + ntu, blk, 0, stream>>>(
        msgA, cnt, Wm_item, bm_item, Wg_item, bg_item, x_item, lng_item, lnb_item, out_item, n_item, nti,
        msgB, cnt + n_item, Wm_user, bm_user, Wg_user, bg_user, x_user, lng_user, lnb_user, out_user, n_user);
}

// Round 7
// 310.909 us; speedup vs baseline: 1.1730x; 1.0900x over previous
//
#include <hip/hip_runtime.h>
#include <hip/hip_bf16.h>

#define DIM 128

typedef short s16x8 __attribute__((ext_vector_type(8)));
typedef float f32x4 __attribute__((ext_vector_type(4)));

__device__ __forceinline__ ushort f2b(float f) {
    __hip_bfloat16 h = __float2bfloat16(f);
    return *reinterpret_cast<ushort*>(&h);
}
__device__ __forceinline__ uint pk2(float a, float b) {
    return (uint)f2b(a) | ((uint)f2b(b) << 16);
}
__device__ __forceinline__ float bl(uint u) { return __uint_as_float(u << 16); }
__device__ __forceinline__ float bh(uint u) { return __uint_as_float(u & 0xffff0000u); }

// Swizzled byte address inside a [rows][128 bf16] LDS tile (256B rows).
__device__ __forceinline__ int swz(int row, int kelem) {
    int b = row * 256 + kelem * 2;
    return b ^ ((row & 7) << 4);
}
__device__ __forceinline__ s16x8 read_frag(const char* lds, int row, int k0) {
    return *(const s16x8*)(lds + swz(row, k0));
}

// ---------------------------------------------------------------------------
// Weight prep: fp32 W[128][128] ([k][n]) -> bf16 fragments, chunk c encodes
// (w,ct,kb,lane): value[j] = W[kb*32+8*(lane>>4)+j][w*32+ct*16+(lane&15)].
// 10 matrices x 2048 chunks; one-time, L2-resident afterwards.
// ---------------------------------------------------------------------------
struct WPtrs { const float* w[10]; };

__global__ __launch_bounds__(256) void prep_weights(WPtrs p, ushort* __restrict__ out) {
    const int id = blockIdx.x * 256 + threadIdx.x;
    const int m = id >> 11;
    if (m >= 10) return;
    const int c = id & 2047;
    const int lane = c & 63;
    const int kb = (c >> 6) & 3;
    const int ct = (c >> 8) & 1;
    const int w = (c >> 9) & 3;
    const int n = w * 32 + ct * 16 + (lane & 15);
    const int k0 = kb * 32 + 8 * (lane >> 4);
    const float* W = p.w[m];
    float v[8];
#pragma unroll
    for (int j = 0; j < 8; ++j) v[j] = W[(size_t)(k0 + j) * 128 + n];
    uint4 u;
    u.x = pk2(v[0], v[1]); u.y = pk2(v[2], v[3]);
    u.z = pk2(v[4], v[5]); u.w = pk2(v[6], v[7]);
    *(uint4*)&out[((size_t)m * 2048 + c) * 8] = u;
}

// Coalesced fragment load: 8 x 16B per thread from frag-ordered weights.
__device__ __forceinline__ void load_bfrag_pk(const ushort* __restrict__ Wf,
                                              s16x8 B[2][4], int w, int l) {
#pragma unroll
    for (int ct = 0; ct < 2; ++ct)
#pragma unroll
        for (int kb = 0; kb < 4; ++kb)
            B[ct][kb] = *(const s16x8*)&Wf[(size_t)(((w * 2 + ct) * 4 + kb) * 64 + l) * 8];
}

__device__ __forceinline__ void stage_f32(const float* __restrict__ src, int r0, int N, char* lds) {
    const int t = threadIdx.x;
    const int r = t >> 2;
    const int k0 = (t & 3) * 32;
    const int row = r0 + r;
#pragma unroll
    for (int c = 0; c < 4; ++c) {
        uint4 u = make_uint4(0, 0, 0, 0);
        if (row < N) {
            const float4 f0 = *(const float4*)&src[(size_t)row * 128 + k0 + c * 8];
            const float4 f1 = *(const float4*)&src[(size_t)row * 128 + k0 + c * 8 + 4];
            u.x = pk2(f0.x, f0.y); u.y = pk2(f0.z, f0.w);
            u.z = pk2(f1.x, f1.y); u.w = pk2(f1.z, f1.w);
        }
        *(uint4*)(lds + swz(r, k0 + c * 8)) = u;
    }
}

__device__ __forceinline__ void stage_b16(const ushort* __restrict__ src, int r0, int N, char* lds) {
    const int t = threadIdx.x;
    const int r = t >> 2;
    const int k0 = (t & 3) * 32;
    const int row = r0 + r;
#pragma unroll
    for (int c = 0; c < 4; ++c) {
        uint4 u = make_uint4(0, 0, 0, 0);
        if (row < N) u = *(const uint4*)&src[(size_t)row * 128 + k0 + c * 8];
        *(uint4*)(lds + swz(r, k0 + c * 8)) = u;
    }
}

// ---------------------------------------------------------------------------
// proj body: one 64-row tile. K (+fused kwa), Q, V sequentially.
// LDS: at 16KB + kwp 4KB.
// ---------------------------------------------------------------------------
__device__ void proj_body(
    const float* __restrict__ x,
    const ushort* __restrict__ WkF, const ushort* __restrict__ WqF, const ushort* __restrict__ WvF,
    const float* __restrict__ Wa,
    ushort* __restrict__ K, ushort* __restrict__ Q, ushort* __restrict__ V,
    float* __restrict__ kwa, int N, int tile, char* mem)
{
    const int t = threadIdx.x, w = t >> 6, l = t & 63;
    const int lr = l & 15, lg = l >> 4;
    char* at = mem;                                        // 16KB A-tile
    float (*kwp)[64][4] = (float (*)[64][4])(mem + 16384); // 4KB partials

    const int r0 = tile << 6;
    stage_f32(x, r0, N, at);
    __syncthreads();

    const int col0 = w * 32 + lr, col1 = col0 + 16;

    // ---- K + fused kwa ----
    {
        s16x8 B[2][4];
        load_bfrag_pk(WkF, B, w, l);
        const float4 waA = *(const float4*)&Wa[col0 * 4];
        const float4 waB = *(const float4*)&Wa[col1 * 4];
#pragma unroll
        for (int rt = 0; rt < 4; ++rt) {
            s16x8 af[4];
#pragma unroll
            for (int kb = 0; kb < 4; ++kb)
                af[kb] = read_frag(at, rt * 16 + lr, kb * 32 + 8 * lg);
            const int rbase = r0 + rt * 16 + 4 * lg;
            f32x4 a0 = {0.f, 0.f, 0.f, 0.f}, a1 = {0.f, 0.f, 0.f, 0.f};
#pragma unroll
            for (int kb = 0; kb < 4; ++kb) {
                a0 = __builtin_amdgcn_mfma_f32_16x16x32_bf16(af[kb], B[0][kb], a0, 0, 0, 0);
                a1 = __builtin_amdgcn_mfma_f32_16x16x32_bf16(af[kb], B[1][kb], a1, 0, 0, 0);
            }
#pragma unroll
            for (int j = 0; j < 4; ++j) {
                if (rbase + j < N) {
                    K[(size_t)(rbase + j) * 128 + col0] = f2b(a0[j]);
                    K[(size_t)(rbase + j) * 128 + col1] = f2b(a1[j]);
                }
            }
#pragma unroll
            for (int j = 0; j < 4; ++j) {
                float p0 = a0[j] * waA.x + a1[j] * waB.x;
                float p1 = a0[j] * waA.y + a1[j] * waB.y;
                float p2 = a0[j] * waA.z + a1[j] * waB.z;
                float p3 = a0[j] * waA.w + a1[j] * waB.w;
#pragma unroll
                for (int off = 8; off; off >>= 1) {
                    p0 += __shfl_xor(p0, off);
                    p1 += __shfl_xor(p1, off);
                    p2 += __shfl_xor(p2, off);
                    p3 += __shfl_xor(p3, off);
                }
                if (lr == 0) {
                    kwp[w][rt * 16 + 4 * lg + j][0] = p0;
                    kwp[w][rt * 16 + 4 * lg + j][1] = p1;
                    kwp[w][rt * 16 + 4 * lg + j][2] = p2;
                    kwp[w][rt * 16 + 4 * lg + j][3] = p3;
                }
            }
        }
    }
    __syncthreads();
    if (t < 64 && r0 + t < N) {
        const float s0 = kwp[0][t][0] + kwp[1][t][0] + kwp[2][t][0] + kwp[3][t][0];
        const float s1 = kwp[0][t][1] + kwp[1][t][1] + kwp[2][t][1] + kwp[3][t][1];
        const float s2 = kwp[0][t][2] + kwp[1][t][2] + kwp[2][t][2] + kwp[3][t][2];
        const float s3 = kwp[0][t][3] + kwp[1][t][3] + kwp[2][t][3] + kwp[3][t][3];
        *(float4*)&kwa[(size_t)(r0 + t) * 4] = make_float4(s0, s1, s2, s3);
    }

    // ---- Q then V ----
    const ushort* Ws[2] = {WqF, WvF};
    ushort* Os[2] = {Q, V};
#pragma unroll
    for (int m = 0; m < 2; ++m) {
        s16x8 B[2][4];
        load_bfrag_pk(Ws[m], B, w, l);
        ushort* O = Os[m];
#pragma unroll
        for (int rt = 0; rt < 4; ++rt) {
            s16x8 af[4];
#pragma unroll
            for (int kb = 0; kb < 4; ++kb)
                af[kb] = read_frag(at, rt * 16 + lr, kb * 32 + 8 * lg);
            const int rbase = r0 + rt * 16 + 4 * lg;
            f32x4 a0 = {0.f, 0.f, 0.f, 0.f}, a1 = {0.f, 0.f, 0.f, 0.f};
#pragma unroll
            for (int kb = 0; kb < 4; ++kb) {
                a0 = __builtin_amdgcn_mfma_f32_16x16x32_bf16(af[kb], B[0][kb], a0, 0, 0, 0);
                a1 = __builtin_amdgcn_mfma_f32_16x16x32_bf16(af[kb], B[1][kb], a1, 0, 0, 0);
            }
#pragma unroll
            for (int j = 0; j < 4; ++j) {
                if (rbase + j < N) {
                    O[(size_t)(rbase + j) * 128 + col0] = f2b(a0[j]);
                    O[(size_t)(rbase + j) * 128 + col1] = f2b(a1[j]);
                }
            }
        }
    }
}

__global__ __launch_bounds__(256) void proj_both(
    const float* __restrict__ xu, const ushort* __restrict__ wfrag,
    const float* __restrict__ Waui,
    ushort* __restrict__ Ku, ushort* __restrict__ Qu, ushort* __restrict__ Vu,
    float* __restrict__ kwa_u, int n_user, int ntu,
    const float* __restrict__ xi,
    const float* __restrict__ Waiu,
    ushort* __restrict__ Ki, ushort* __restrict__ Qi, ushort* __restrict__ Vi,
    float* __restrict__ kwa_i, int n_item)
{
    __shared__ char mem[20480];
    const int b = blockIdx.x;
    if (b < ntu)
        proj_body(xu, wfrag + 0 * 16384, wfrag + 1 * 16384, wfrag + 2 * 16384,
                  Waui, Ku, Qu, Vu, kwa_u, n_user, b, mem);
    else
        proj_body(xi, wfrag + 3 * 16384, wfrag + 4 * 16384, wfrag + 5 * 16384,
                  Waiu, Ki, Qi, Vi, kwa_i, n_item, b - ntu, mem);
}

// ---------------------------------------------------------------------------
__global__ __launch_bounds__(256) void hist_kernel(
    const int* __restrict__ dst_i, const int* __restrict__ dst_u,
    int* __restrict__ cnt, int ni, int E)
{
    const int e = blockIdx.x * blockDim.x + threadIdx.x;
    if (e < E) atomicAdd(&cnt[dst_i[e]], 1);
    else if (e < 2 * E) atomicAdd(&cnt[ni + dst_u[e - E]], 1);
}

__global__ __launch_bounds__(256) void alloc_kernel(
    const int* __restrict__ cnt, int* __restrict__ base,
    int* __restrict__ fill, int* __restrict__ cursor, int n)
{
    const int d = blockIdx.x * blockDim.x + threadIdx.x;
    const int lane = threadIdx.x & 63;
    int c = (d < n) ? cnt[d] : 0;
    int sc = c;
#pragma unroll
    for (int off = 1; off < 64; off <<= 1) {
        int t = __shfl_up(sc, off);
        if (lane >= off) sc += t;
    }
    const int total = __shfl(sc, 63);
    int wb = 0;
    if (lane == 63) wb = atomicAdd(cursor, total);
    wb = __shfl(wb, 63);
    if (d < n) {
        const int b = wb + sc - c;
        base[d] = b;
        fill[d] = b;
    }
}

template<typename IT>
__global__ __launch_bounds__(256) void scatter_kernel(
    const int* __restrict__ ei_ui, const int* __restrict__ ei_iu,
    int* __restrict__ fill, IT* __restrict__ bucket, int ni, int E)
{
    const int e = blockIdx.x * blockDim.x + threadIdx.x;
    if (e < E) {
        const int pos = atomicAdd(&fill[ei_ui[E + e]], 1);
        bucket[pos] = (IT)ei_ui[e];
    } else if (e < 2 * E) {
        const int pos = atomicAdd(&fill[ni + ei_iu[E + e - E]], 1);
        bucket[pos] = (IT)ei_iu[e - E];
    }
}

// ---------------------------------------------------------------------------
// agg2: one wave per dst over the concatenated dst space. 4-wide unroll.
// ---------------------------------------------------------------------------
template<typename IT>
__global__ __launch_bounds__(256) void agg2_kernel(
    const int* __restrict__ base, const int* __restrict__ cnt, const IT* __restrict__ bsrc,
    const ushort* __restrict__ Ku, const ushort* __restrict__ Qi, const ushort* __restrict__ Vu,
    const float* __restrict__ kwa_u, ushort* __restrict__ msgA,
    const ushort* __restrict__ Ki, const ushort* __restrict__ Qu, const ushort* __restrict__ Vi,
    const float* __restrict__ kwa_i, ushort* __restrict__ msgB,
    int n_item, int ntot)
{
    const int widx = (int)((blockIdx.x * blockDim.x + threadIdx.x) >> 6);
    if (widx >= ntot) return;
    const bool item_side = widx < n_item;
    const int d = item_side ? widx : widx - n_item;
    const ushort* K  = item_side ? Ku : Ki;
    const ushort* Q  = item_side ? Qi : Qu;
    const ushort* V  = item_side ? Vu : Vi;
    const float* kwa = item_side ? kwa_u : kwa_i;
    ushort* msg      = item_side ? msgA : msgB;

    const int l = threadIdx.x & 63;
    const int h = l >> 4;
    const float inv = 0.17677669529663687f;   // 1/sqrt(32)
    const uint qu = *(const uint*)&Q[(size_t)d * 128 + 2 * l];
    const float qx = bl(qu), qy = bh(qu);
    const int b = base[widx], c = cnt[widx];
    float mx = 0.f, my = 0.f;

    for (int i = 0; i < c; i += 4) {
        const int s0 = (int)bsrc[b + i];
        const int s1 = (i + 1 < c) ? (int)bsrc[b + i + 1] : s0;
        const int s2 = (i + 2 < c) ? (int)bsrc[b + i + 2] : s0;
        const int s3 = (i + 3 < c) ? (int)bsrc[b + i + 3] : s0;

        const uint ku0 = *(const uint*)&K[(size_t)s0 * 128 + 2 * l];
        const uint ku1 = *(const uint*)&K[(size_t)s1 * 128 + 2 * l];
        const uint ku2 = *(const uint*)&K[(size_t)s2 * 128 + 2 * l];
        const uint ku3 = *(const uint*)&K[(size_t)s3 * 128 + 2 * l];
        const uint vu0 = *(const uint*)&V[(size_t)s0 * 128 + 2 * l];
        const uint vu1 = *(const uint*)&V[(size_t)s1 * 128 + 2 * l];
        const uint vu2 = *(const uint*)&V[(size_t)s2 * 128 + 2 * l];
        const uint vu3 = *(const uint*)&V[(size_t)s3 * 128 + 2 * l];
        const float kw0 = kwa[(size_t)s0 * 4 + h];
        const float kw1 = kwa[(size_t)s1 * 4 + h];
        const float kw2 = kwa[(size_t)s2 * 4 + h];
        const float kw3 = kwa[(size_t)s3 * 4 + h];

        float p0 = bl(ku0) * qx + bh(ku0) * qy;
        float p1 = bl(ku1) * qx + bh(ku1) * qy;
        float p2 = bl(ku2) * qx + bh(ku2) * qy;
        float p3 = bl(ku3) * qx + bh(ku3) * qy;
#pragma unroll
        for (int off = 8; off; off >>= 1) {
            p0 += __shfl_xor(p0, off);
            p1 += __shfl_xor(p1, off);
            p2 += __shfl_xor(p2, off);
            p3 += __shfl_xor(p3, off);
        }
        const float e0 = __expf(p0 * inv + kw0);
        const float e1 = __expf(p1 * inv + kw1);
        const float e2 = __expf(p2 * inv + kw2);
        const float e3 = __expf(p3 * inv + kw3);
        float es0 = e0 + __shfl_xor(e0, 16);
        float es1 = e1 + __shfl_xor(e1, 16);
        float es2 = e2 + __shfl_xor(e2, 16);
        float es3 = e3 + __shfl_xor(e3, 16);
        es0 += __shfl_xor(es0, 32);
        es1 += __shfl_xor(es1, 32);
        es2 += __shfl_xor(es2, 32);
        es3 += __shfl_xor(es3, 32);
        const float a0 = __fdividef(e0, es0);
        const float a1 = (i + 1 < c) ? __fdividef(e1, es1) : 0.f;
        const float a2 = (i + 2 < c) ? __fdividef(e2, es2) : 0.f;
        const float a3 = (i + 3 < c) ? __fdividef(e3, es3) : 0.f;

        mx += a0 * bl(vu0) + a1 * bl(vu1) + a2 * bl(vu2) + a3 * bl(vu3);
        my += a0 * bh(vu0) + a1 * bh(vu1) + a2 * bh(vu2) + a3 * bh(vu3);
    }
    *(uint*)&msg[(size_t)d * 128 + 2 * l] = pk2(mx, my);
}

// ---------------------------------------------------------------------------
// post body: one 64-row tile of LN(((A@Wm)*rs+bm)@Wg + bg + resid)*g + b.
// Dual LDS buffers (at -> tt), 2 barriers. LDS: 16+16+2.5KB.
// ---------------------------------------------------------------------------
__device__ void post_body(
    const ushort* __restrict__ A, const int* __restrict__ deg,
    const ushort* __restrict__ WmF, const float* __restrict__ bm,
    const ushort* __restrict__ WgF, const float* __restrict__ bg,
    const float* __restrict__ resid, const float* __restrict__ gamma,
    const float* __restrict__ beta, float* __restrict__ out, int N, int tile, char* mem)
{
    const int t = threadIdx.x, w = t >> 6, l = t & 63;
    const int lr = l & 15, lg = l >> 4;
    char* at = mem;                                      // 16KB input tile
    char* tt = mem + 16384;                              // 16KB tmp tile
    float2 (*part)[64] = (float2 (*)[64])(mem + 32768);  // 2KB
    float2* lnp = (float2*)(mem + 32768 + 2048);         // 512B

    const int col0 = w * 32 + lr, col1 = col0 + 16;
    const int r0 = tile << 6;
    stage_b16(A, r0, N, at);
    __syncthreads();

    // Stage 1: tmp = A@Wm * rs + bm  (at -> tt, no intra-stage barriers)
    {
        s16x8 B[2][4];
        load_bfrag_pk(WmF, B, w, l);
        const float bm0 = bm[col0], bm1 = bm[col1];
#pragma unroll
        for (int rt = 0; rt < 4; ++rt) {
            s16x8 af[4];
#pragma unroll
            for (int kb = 0; kb < 4; ++kb)
                af[kb] = read_frag(at, rt * 16 + lr, kb * 32 + 8 * lg);
            const int rbase = r0 + rt * 16 + 4 * lg;
            float rs[4];
#pragma unroll
            for (int j = 0; j < 4; ++j)
                rs[j] = (rbase + j < N) ? 1.0f / fmaxf((float)deg[rbase + j], 1e-8f) : 0.f;
            f32x4 a0 = {0.f, 0.f, 0.f, 0.f}, a1 = {0.f, 0.f, 0.f, 0.f};
#pragma unroll
            for (int kb = 0; kb < 4; ++kb) {
                a0 = __builtin_amdgcn_mfma_f32_16x16x32_bf16(af[kb], B[0][kb], a0, 0, 0, 0);
                a1 = __builtin_amdgcn_mfma_f32_16x16x32_bf16(af[kb], B[1][kb], a1, 0, 0, 0);
            }
#pragma unroll
            for (int j = 0; j < 4; ++j) {
                *(ushort*)(tt + swz(rt * 16 + 4 * lg + j, col0)) = f2b(a0[j] * rs[j] + bm0);
                *(ushort*)(tt + swz(rt * 16 + 4 * lg + j, col1)) = f2b(a1[j] * rs[j] + bm1);
            }
        }
    }
    __syncthreads();

    // Stage 2: v = tmp@Wg + bg + resid, then LayerNorm.
    float v[4][2][4];
    {
        s16x8 B[2][4];
        load_bfrag_pk(WgF, B, w, l);
        const float bg0 = bg[col0], bg1 = bg[col1];
#pragma unroll
        for (int rt = 0; rt < 4; ++rt) {
            s16x8 af[4];
#pragma unroll
            for (int kb = 0; kb < 4; ++kb)
                af[kb] = read_frag(tt, rt * 16 + lr, kb * 32 + 8 * lg);
            const int rbase = r0 + rt * 16 + 4 * lg;
            f32x4 a0 = {0.f, 0.f, 0.f, 0.f}, a1 = {0.f, 0.f, 0.f, 0.f};
#pragma unroll
            for (int kb = 0; kb < 4; ++kb) {
                a0 = __builtin_amdgcn_mfma_f32_16x16x32_bf16(af[kb], B[0][kb], a0, 0, 0, 0);
                a1 = __builtin_amdgcn_mfma_f32_16x16x32_bf16(af[kb], B[1][kb], a1, 0, 0, 0);
            }
#pragma unroll
            for (int j = 0; j < 4; ++j) {
                const bool ok = (rbase + j < N);
                const float rv0 = ok ? resid[(size_t)(rbase + j) * 128 + col0] : 0.f;
                const float rv1 = ok ? resid[(size_t)(rbase + j) * 128 + col1] : 0.f;
                v[rt][0][j] = a0[j] + bg0 + rv0;
                v[rt][1][j] = a1[j] + bg1 + rv1;
            }
        }
    }
#pragma unroll
    for (int rt = 0; rt < 4; ++rt)
#pragma unroll
        for (int j = 0; j < 4; ++j) {
            float s = v[rt][0][j] + v[rt][1][j];
            float q = v[rt][0][j] * v[rt][0][j] + v[rt][1][j] * v[rt][1][j];
            s += __shfl_xor(s, 8); q += __shfl_xor(q, 8);
            s += __shfl_xor(s, 4); q += __shfl_xor(q, 4);
            s += __shfl_xor(s, 2); q += __shfl_xor(q, 2);
            s += __shfl_xor(s, 1); q += __shfl_xor(q, 1);
            if (lr == 0) part[w][rt * 16 + 4 * lg + j] = make_float2(s, q);
        }
    __syncthreads();
    if (t < 64) {
        const float S = part[0][t].x + part[1][t].x + part[2][t].x + part[3][t].x;
        const float Qq = part[0][t].y + part[1][t].y + part[2][t].y + part[3][t].y;
        const float mu = S * (1.f / 128.f);
        const float var = Qq * (1.f / 128.f) - mu * mu;
        lnp[t] = make_float2(mu, rsqrtf(var + 1e-5f));
    }
    __syncthreads();
    const float g0 = gamma[col0], g1 = gamma[col1];
    const float be0 = beta[col0], be1 = beta[col1];
#pragma unroll
    for (int rt = 0; rt < 4; ++rt) {
        const int rbase = r0 + rt * 16 + 4 * lg;
#pragma unroll
        for (int j = 0; j < 4; ++j) {
            const float2 mp = lnp[rt * 16 + 4 * lg + j];
            if (rbase + j < N) {
                out[(size_t)(rbase + j) * 128 + col0] = (v[rt][0][j] - mp.x) * mp.y * g0 + be0;
                out[(size_t)(rbase + j) * 128 + col1] = (v[rt][1][j] - mp.x) * mp.y * g1 + be1;
            }
        }
    }
}

__global__ __launch_bounds__(256) void post2_kernel(
    const ushort* __restrict__ msgA, const int* __restrict__ cnt_i,
    const ushort* __restrict__ wfrag,
    const float* __restrict__ bmi, const float* __restrict__ bgi,
    const float* __restrict__ xi, const float* __restrict__ lngi, const float* __restrict__ lnbi,
    float* __restrict__ out_item, int n_item, int nti,
    const ushort* __restrict__ msgB, const int* __restrict__ cnt_u,
    const float* __restrict__ bmu, const float* __restrict__ bgu,
    const float* __restrict__ xu, const float* __restrict__ lngu, const float* __restrict__ lnbu,
    float* __restrict__ out_user, int n_user)
{
    __shared__ char mem[32768 + 2048 + 512];
    const int b = blockIdx.x;
    if (b < nti)
        post_body(msgA, cnt_i, wfrag + 6 * 16384, bmi, wfrag + 7 * 16384, bgi,
                  xi, lngi, lnbi, out_item, n_item, b, mem);
    else
        post_body(msgB, cnt_u, wfrag + 8 * 16384, bmu, wfrag + 9 * 16384, bgu,
                  xu, lngu, lnbu, out_user, n_user, b - nti, mem);
}

// ---------------------------------------------------------------------------
extern "C" void kernel_launch(void* const* d_in, const int* in_sizes, int n_in,
                              void* d_out, int out_size, void* d_ws, size_t ws_size,
                              hipStream_t stream)
{
    const float* x_user  = (const float*)d_in[0];
    const float* x_item  = (const float*)d_in[1];
    const int*   ei_ui   = (const int*)d_in[2];
    const int*   ei_iu   = (const int*)d_in[3];
    const float* Wk_user = (const float*)d_in[4];
    const float* Wq_user = (const float*)d_in[5];
    const float* Wv_user = (const float*)d_in[6];
    const float* Wk_item = (const float*)d_in[7];
    const float* Wq_item = (const float*)d_in[8];
    const float* Wv_item = (const float*)d_in[9];
    const float* Wa_ui   = (const float*)d_in[10];
    const float* Wa_iu   = (const float*)d_in[11];
    const float* Wm_user = (const float*)d_in[12];
    const float* bm_user = (const float*)d_in[13];
    const float* Wm_item = (const float*)d_in[14];
    const float* bm_item = (const float*)d_in[15];
    const float* Wg_user = (const float*)d_in[16];
    const float* bg_user = (const float*)d_in[17];
    const float* Wg_item = (const float*)d_in[18];
    const float* bg_item = (const float*)d_in[19];
    const float* lng_user = (const float*)d_in[20];
    const float* lnb_user = (const float*)d_in[21];
    const float* lng_item = (const float*)d_in[22];
    const float* lnb_item = (const float*)d_in[23];

    const int n_user = in_sizes[0] / DIM;
    const int n_item = in_sizes[1] / DIM;
    const int E = in_sizes[2] / 2;
    const int nmax = (n_user > n_item) ? n_user : n_item;
    const int ntot = n_user + n_item;
    const size_t nf = (size_t)nmax * DIM;

    ushort* Ku   = (ushort*)d_ws;
    ushort* Qu   = Ku + nf;
    ushort* Vu   = Qu + nf;
    ushort* Ki   = Vu + nf;
    ushort* Qi   = Ki + nf;
    ushort* Vi   = Qi + nf;
    ushort* msgA = Vi + nf;
    ushort* msgB = msgA + nf;
    float* kwa_u = (float*)(msgB + nf);
    float* kwa_i = kwa_u + (size_t)nmax * 4;
    int* cnt     = (int*)(kwa_i + (size_t)nmax * 4);  // [ntot] items then users
    int* cursor  = cnt + ntot;                        // [4]
    int* basep   = cursor + 4;                        // [ntot]
    int* fill    = basep + ntot;                      // [ntot]
    ushort* bucket16 = (ushort*)(fill + ntot);        // [2E]
    ushort* wfrag    = bucket16 + 2 * (size_t)E;      // [10*16384]

    float* out_user = (float*)d_out;
    float* out_item = out_user + (size_t)n_user * DIM;

    const dim3 blk(256);
    const int ntu = (n_user + 63) / 64, nti = (n_item + 63) / 64;
    const int histB = (2 * E + 255) / 256;

    hipMemsetAsync(cnt, 0, ((size_t)ntot + 4) * sizeof(int), stream);

    WPtrs wp;
    wp.w[0] = Wk_user; wp.w[1] = Wq_user; wp.w[2] = Wv_user;
    wp.w[3] = Wk_item; wp.w[4] = Wq_item; wp.w[5] = Wv_item;
    wp.w[6] = Wm_item; wp.w[7] = Wg_item;
    wp.w[8] = Wm_user; wp.w[9] = Wg_user;
    prep_weights<<<80, blk, 0, stream>>>(wp, wfrag);

    proj_both<<<ntu + nti, blk, 0, stream>>>(
        x_user, wfrag, Wa_ui, Ku, Qu, Vu, kwa_u, n_user, ntu,
        x_item, Wa_iu, Ki, Qi, Vi, kwa_i, n_item);

    hist_kernel<<<histB, blk, 0, stream>>>(ei_ui + E, ei_iu + E, cnt, n_item, E);
    alloc_kernel<<<(ntot + 255) / 256, blk, 0, stream>>>(cnt, basep, fill, cursor, ntot);

    if (nmax <= 65535) {
        scatter_kernel<ushort><<<histB, blk, 0, stream>>>(ei_ui, ei_iu, fill, bucket16, n_item, E);
        agg2_kernel<ushort><<<(ntot + 3) / 4, blk, 0, stream>>>(
            basep, cnt, (const ushort*)bucket16,
            Ku, Qi, Vu, kwa_u, msgA,
            Ki, Qu, Vi, kwa_i, msgB,
            n_item, ntot);
    } else {
        scatter_kernel<int><<<histB, blk, 0, stream>>>(ei_ui, ei_iu, fill, (int*)bucket16, n_item, E);
        agg2_kernel<int><<<(ntot + 3) / 4, blk, 0, stream>>>(
            basep, cnt, (const int*)bucket16,
            Ku, Qi, Vu, kwa_u, msgA,
            Ki, Qu, Vi, kwa_i, msgB,
            n_item, ntot);
    }

    post2_kernel<<<nti + ntu, blk, 0, stream>>>(
        msgA, cnt, wfrag, bm_item, bg_item, x_item, lng_item, lnb_item, out_item, n_item, nti,
        msgB, cnt + n_item, bm_user, bg_user, x_user, lng_user, lnb_user, out_user, n_user);
}

// Round 8
// 306.288 us; speedup vs baseline: 1.1907x; 1.0151x over previous
//
#include <hip/hip_runtime.h>
#include <hip/hip_bf16.h>

#define DIM 128

typedef short s16x8 __attribute__((ext_vector_type(8)));
typedef float f32x4 __attribute__((ext_vector_type(4)));

__device__ __forceinline__ ushort f2b(float f) {
    __hip_bfloat16 h = __float2bfloat16(f);
    return *reinterpret_cast<ushort*>(&h);
}
__device__ __forceinline__ uint pk2(float a, float b) {
    return (uint)f2b(a) | ((uint)f2b(b) << 16);
}
__device__ __forceinline__ float bl(uint u) { return __uint_as_float(u << 16); }
__device__ __forceinline__ float bh(uint u) { return __uint_as_float(u & 0xffff0000u); }

// Swizzled byte address inside a [rows][128 bf16] LDS tile (256B rows).
__device__ __forceinline__ int swz(int row, int kelem) {
    int b = row * 256 + kelem * 2;
    return b ^ ((row & 7) << 4);
}
__device__ __forceinline__ s16x8 read_frag(const char* lds, int row, int k0) {
    return *(const s16x8*)(lds + swz(row, k0));
}

// ---------------------------------------------------------------------------
// prep_hist: [0,80) blocks: weight frag-pack; rest: degree histogram.
// Both LDS-free / low-VGPR (matching footprints — safe to fuse).
// ---------------------------------------------------------------------------
struct WPtrs { const float* w[10]; };

__global__ __launch_bounds__(256) void prep_hist(
    WPtrs p, ushort* __restrict__ out,
    const int* __restrict__ dst_i, const int* __restrict__ dst_u,
    int* __restrict__ cnt, int ni, int E)
{
    const int id = blockIdx.x * 256 + threadIdx.x;
    if (id < 20480) {
        const int m = id >> 11;
        const int c = id & 2047;
        const int lane = c & 63;
        const int kb = (c >> 6) & 3;
        const int ct = (c >> 8) & 1;
        const int w = (c >> 9) & 3;
        const int n = w * 32 + ct * 16 + (lane & 15);
        const int k0 = kb * 32 + 8 * (lane >> 4);
        const float* W = p.w[m];
        float v[8];
#pragma unroll
        for (int j = 0; j < 8; ++j) v[j] = W[(size_t)(k0 + j) * 128 + n];
        uint4 u;
        u.x = pk2(v[0], v[1]); u.y = pk2(v[2], v[3]);
        u.z = pk2(v[4], v[5]); u.w = pk2(v[6], v[7]);
        *(uint4*)&out[((size_t)m * 2048 + c) * 8] = u;
    } else {
        const int gid = id - 20480;
        if (gid < E) atomicAdd(&cnt[dst_i[gid]], 1);
        else if (gid < 2 * E) atomicAdd(&cnt[ni + dst_u[gid - E]], 1);
    }
}

// Coalesced fragment load: 8 x 16B per thread from frag-ordered weights.
__device__ __forceinline__ void load_bfrag_pk(const ushort* __restrict__ Wf,
                                              s16x8 B[2][4], int w, int l) {
#pragma unroll
    for (int ct = 0; ct < 2; ++ct)
#pragma unroll
        for (int kb = 0; kb < 4; ++kb)
            B[ct][kb] = *(const s16x8*)&Wf[(size_t)(((w * 2 + ct) * 4 + kb) * 64 + l) * 8];
}

__device__ __forceinline__ void stage_f32(const float* __restrict__ src, int r0, int N, char* lds) {
    const int t = threadIdx.x;
    const int r = t >> 2;
    const int k0 = (t & 3) * 32;
    const int row = r0 + r;
#pragma unroll
    for (int c = 0; c < 4; ++c) {
        uint4 u = make_uint4(0, 0, 0, 0);
        if (row < N) {
            const float4 f0 = *(const float4*)&src[(size_t)row * 128 + k0 + c * 8];
            const float4 f1 = *(const float4*)&src[(size_t)row * 128 + k0 + c * 8 + 4];
            u.x = pk2(f0.x, f0.y); u.y = pk2(f0.z, f0.w);
            u.z = pk2(f1.x, f1.y); u.w = pk2(f1.z, f1.w);
        }
        *(uint4*)(lds + swz(r, k0 + c * 8)) = u;
    }
}

__device__ __forceinline__ void stage_b16(const ushort* __restrict__ src, int r0, int N, char* lds) {
    const int t = threadIdx.x;
    const int r = t >> 2;
    const int k0 = (t & 3) * 32;
    const int row = r0 + r;
#pragma unroll
    for (int c = 0; c < 4; ++c) {
        uint4 u = make_uint4(0, 0, 0, 0);
        if (row < N) u = *(const uint4*)&src[(size_t)row * 128 + k0 + c * 8];
        *(uint4*)(lds + swz(r, k0 + c * 8)) = u;
    }
}

// ---------------------------------------------------------------------------
// proj body (unchanged from round 7): one 64-row tile, K(+kwa), Q, V.
// ---------------------------------------------------------------------------
__device__ void proj_body(
    const float* __restrict__ x,
    const ushort* __restrict__ WkF, const ushort* __restrict__ WqF, const ushort* __restrict__ WvF,
    const float* __restrict__ Wa,
    ushort* __restrict__ K, ushort* __restrict__ Q, ushort* __restrict__ V,
    float* __restrict__ kwa, int N, int tile, char* mem)
{
    const int t = threadIdx.x, w = t >> 6, l = t & 63;
    const int lr = l & 15, lg = l >> 4;
    char* at = mem;
    float (*kwp)[64][4] = (float (*)[64][4])(mem + 16384);

    const int r0 = tile << 6;
    stage_f32(x, r0, N, at);
    __syncthreads();

    const int col0 = w * 32 + lr, col1 = col0 + 16;

    {
        s16x8 B[2][4];
        load_bfrag_pk(WkF, B, w, l);
        const float4 waA = *(const float4*)&Wa[col0 * 4];
        const float4 waB = *(const float4*)&Wa[col1 * 4];
#pragma unroll
        for (int rt = 0; rt < 4; ++rt) {
            s16x8 af[4];
#pragma unroll
            for (int kb = 0; kb < 4; ++kb)
                af[kb] = read_frag(at, rt * 16 + lr, kb * 32 + 8 * lg);
            const int rbase = r0 + rt * 16 + 4 * lg;
            f32x4 a0 = {0.f, 0.f, 0.f, 0.f}, a1 = {0.f, 0.f, 0.f, 0.f};
#pragma unroll
            for (int kb = 0; kb < 4; ++kb) {
                a0 = __builtin_amdgcn_mfma_f32_16x16x32_bf16(af[kb], B[0][kb], a0, 0, 0, 0);
                a1 = __builtin_amdgcn_mfma_f32_16x16x32_bf16(af[kb], B[1][kb], a1, 0, 0, 0);
            }
#pragma unroll
            for (int j = 0; j < 4; ++j) {
                if (rbase + j < N) {
                    K[(size_t)(rbase + j) * 128 + col0] = f2b(a0[j]);
                    K[(size_t)(rbase + j) * 128 + col1] = f2b(a1[j]);
                }
            }
#pragma unroll
            for (int j = 0; j < 4; ++j) {
                float p0 = a0[j] * waA.x + a1[j] * waB.x;
                float p1 = a0[j] * waA.y + a1[j] * waB.y;
                float p2 = a0[j] * waA.z + a1[j] * waB.z;
                float p3 = a0[j] * waA.w + a1[j] * waB.w;
#pragma unroll
                for (int off = 8; off; off >>= 1) {
                    p0 += __shfl_xor(p0, off);
                    p1 += __shfl_xor(p1, off);
                    p2 += __shfl_xor(p2, off);
                    p3 += __shfl_xor(p3, off);
                }
                if (lr == 0) {
                    kwp[w][rt * 16 + 4 * lg + j][0] = p0;
                    kwp[w][rt * 16 + 4 * lg + j][1] = p1;
                    kwp[w][rt * 16 + 4 * lg + j][2] = p2;
                    kwp[w][rt * 16 + 4 * lg + j][3] = p3;
                }
            }
        }
    }
    __syncthreads();
    if (t < 64 && r0 + t < N) {
        const float s0 = kwp[0][t][0] + kwp[1][t][0] + kwp[2][t][0] + kwp[3][t][0];
        const float s1 = kwp[0][t][1] + kwp[1][t][1] + kwp[2][t][1] + kwp[3][t][1];
        const float s2 = kwp[0][t][2] + kwp[1][t][2] + kwp[2][t][2] + kwp[3][t][2];
        const float s3 = kwp[0][t][3] + kwp[1][t][3] + kwp[2][t][3] + kwp[3][t][3];
        *(float4*)&kwa[(size_t)(r0 + t) * 4] = make_float4(s0, s1, s2, s3);
    }

    const ushort* Ws[2] = {WqF, WvF};
    ushort* Os[2] = {Q, V};
#pragma unroll
    for (int m = 0; m < 2; ++m) {
        s16x8 B[2][4];
        load_bfrag_pk(Ws[m], B, w, l);
        ushort* O = Os[m];
#pragma unroll
        for (int rt = 0; rt < 4; ++rt) {
            s16x8 af[4];
#pragma unroll
            for (int kb = 0; kb < 4; ++kb)
                af[kb] = read_frag(at, rt * 16 + lr, kb * 32 + 8 * lg);
            const int rbase = r0 + rt * 16 + 4 * lg;
            f32x4 a0 = {0.f, 0.f, 0.f, 0.f}, a1 = {0.f, 0.f, 0.f, 0.f};
#pragma unroll
            for (int kb = 0; kb < 4; ++kb) {
                a0 = __builtin_amdgcn_mfma_f32_16x16x32_bf16(af[kb], B[0][kb], a0, 0, 0, 0);
                a1 = __builtin_amdgcn_mfma_f32_16x16x32_bf16(af[kb], B[1][kb], a1, 0, 0, 0);
            }
#pragma unroll
            for (int j = 0; j < 4; ++j) {
                if (rbase + j < N) {
                    O[(size_t)(rbase + j) * 128 + col0] = f2b(a0[j]);
                    O[(size_t)(rbase + j) * 128 + col1] = f2b(a1[j]);
                }
            }
        }
    }
}

__global__ __launch_bounds__(256) void proj_both(
    const float* __restrict__ xu, const ushort* __restrict__ wfrag,
    const float* __restrict__ Waui,
    ushort* __restrict__ Ku, ushort* __restrict__ Qu, ushort* __restrict__ Vu,
    float* __restrict__ kwa_u, int n_user, int ntu,
    const float* __restrict__ xi,
    const float* __restrict__ Waiu,
    ushort* __restrict__ Ki, ushort* __restrict__ Qi, ushort* __restrict__ Vi,
    float* __restrict__ kwa_i, int n_item)
{
    __shared__ char mem[20480];
    const int b = blockIdx.x;
    if (b < ntu)
        proj_body(xu, wfrag + 0 * 16384, wfrag + 1 * 16384, wfrag + 2 * 16384,
                  Waui, Ku, Qu, Vu, kwa_u, n_user, b, mem);
    else
        proj_body(xi, wfrag + 3 * 16384, wfrag + 4 * 16384, wfrag + 5 * 16384,
                  Waiu, Ki, Qi, Vi, kwa_i, n_item, b - ntu, mem);
}

// ---------------------------------------------------------------------------
__global__ __launch_bounds__(256) void alloc_kernel(
    const int* __restrict__ cnt, int* __restrict__ base,
    int* __restrict__ fill, int* __restrict__ cursor, int n)
{
    const int d = blockIdx.x * blockDim.x + threadIdx.x;
    const int lane = threadIdx.x & 63;
    int c = (d < n) ? cnt[d] : 0;
    int sc = c;
#pragma unroll
    for (int off = 1; off < 64; off <<= 1) {
        int t = __shfl_up(sc, off);
        if (lane >= off) sc += t;
    }
    const int total = __shfl(sc, 63);
    int wb = 0;
    if (lane == 63) wb = atomicAdd(cursor, total);
    wb = __shfl(wb, 63);
    if (d < n) {
        const int b = wb + sc - c;
        base[d] = b;
        fill[d] = b;
    }
}

template<typename IT>
__global__ __launch_bounds__(256) void scatter_kernel(
    const int* __restrict__ ei_ui, const int* __restrict__ ei_iu,
    int* __restrict__ fill, IT* __restrict__ bucket, int ni, int E)
{
    const int e = blockIdx.x * blockDim.x + threadIdx.x;
    if (e < E) {
        const int pos = atomicAdd(&fill[ei_ui[E + e]], 1);
        bucket[pos] = (IT)ei_ui[e];
    } else if (e < 2 * E) {
        const int pos = atomicAdd(&fill[ni + ei_iu[E + e - E]], 1);
        bucket[pos] = (IT)ei_iu[e - E];
    }
}

// ---------------------------------------------------------------------------
// agg4: one 4-lane group per dst; lane li owns head li = dims [32li, 32li+32).
// Dot is lane-local (no shuffles); softmax = 2 shfl_xor within the group.
// ---------------------------------------------------------------------------
__device__ __forceinline__ void unpack8(uint4 u, float* q) {
    q[0] = bl(u.x); q[1] = bh(u.x); q[2] = bl(u.y); q[3] = bh(u.y);
    q[4] = bl(u.z); q[5] = bh(u.z); q[6] = bl(u.w); q[7] = bh(u.w);
}
__device__ __forceinline__ float dot8(uint4 u, const float* q) {
    return bl(u.x) * q[0] + bh(u.x) * q[1] + bl(u.y) * q[2] + bh(u.y) * q[3]
         + bl(u.z) * q[4] + bh(u.z) * q[5] + bl(u.w) * q[6] + bh(u.w) * q[7];
}
__device__ __forceinline__ void acc8(uint4 u, float a, float* acc) {
    acc[0] += a * bl(u.x); acc[1] += a * bh(u.x);
    acc[2] += a * bl(u.y); acc[3] += a * bh(u.y);
    acc[4] += a * bl(u.z); acc[5] += a * bh(u.z);
    acc[6] += a * bl(u.w); acc[7] += a * bh(u.w);
}

template<typename IT>
__global__ __launch_bounds__(256) void agg4_kernel(
    const int* __restrict__ base, const int* __restrict__ cnt, const IT* __restrict__ bsrc,
    const ushort* __restrict__ Ku, const ushort* __restrict__ Qi, const ushort* __restrict__ Vu,
    const float* __restrict__ kwa_u, ushort* __restrict__ msgA,
    const ushort* __restrict__ Ki, const ushort* __restrict__ Qu, const ushort* __restrict__ Vi,
    const float* __restrict__ kwa_i, ushort* __restrict__ msgB,
    int n_item, int ntot)
{
    const int gid = (int)((blockIdx.x * blockDim.x + threadIdx.x) >> 2);
    if (gid >= ntot) return;
    const int li = threadIdx.x & 3;          // head index / dim quarter
    const bool item_side = gid < n_item;
    const int d = item_side ? gid : gid - n_item;
    const ushort* K  = item_side ? Ku : Ki;
    const ushort* Q  = item_side ? Qi : Qu;
    const ushort* V  = item_side ? Vu : Vi;
    const float* kwa = item_side ? kwa_u : kwa_i;
    ushort* msg      = item_side ? msgA : msgB;

    const float inv = 0.17677669529663687f;   // 1/sqrt(32)

    float q[32];
    {
        const uint4* qp = (const uint4*)&Q[(size_t)d * 128 + li * 32];
#pragma unroll
        for (int m = 0; m < 4; ++m) unpack8(qp[m], &q[m * 8]);
    }
    float acc[32];
#pragma unroll
    for (int m = 0; m < 32; ++m) acc[m] = 0.f;

    const int b = base[gid], c = cnt[gid];
    int s = (c > 0) ? (int)bsrc[b] : 0;
    for (int i = 0; i < c; ++i) {
        const int snext = (i + 1 < c) ? (int)bsrc[b + i + 1] : s;   // prefetch
        const uint4* kp = (const uint4*)&K[(size_t)s * 128 + li * 32];
        const uint4* vp = (const uint4*)&V[(size_t)s * 128 + li * 32];
        const uint4 k0 = kp[0], k1 = kp[1], k2 = kp[2], k3 = kp[3];
        const uint4 v0 = vp[0], v1 = vp[1], v2 = vp[2], v3 = vp[3];
        const float kw = kwa[(size_t)s * 4 + li];

        float p = dot8(k0, &q[0]) + dot8(k1, &q[8]) + dot8(k2, &q[16]) + dot8(k3, &q[24]);
        const float e = __expf(p * inv + kw);
        float es = e + __shfl_xor(e, 1);
        es += __shfl_xor(es, 2);
        const float att = __fdividef(e, es);

        acc8(v0, att, &acc[0]);
        acc8(v1, att, &acc[8]);
        acc8(v2, att, &acc[16]);
        acc8(v3, att, &acc[24]);
        s = snext;
    }

    uint4* mp = (uint4*)&msg[(size_t)d * 128 + li * 32];
#pragma unroll
    for (int m = 0; m < 4; ++m) {
        uint4 o;
        o.x = pk2(acc[m * 8 + 0], acc[m * 8 + 1]);
        o.y = pk2(acc[m * 8 + 2], acc[m * 8 + 3]);
        o.z = pk2(acc[m * 8 + 4], acc[m * 8 + 5]);
        o.w = pk2(acc[m * 8 + 6], acc[m * 8 + 7]);
        mp[m] = o;
    }
}

// ---------------------------------------------------------------------------
// post body (unchanged from round 7)
// ---------------------------------------------------------------------------
__device__ void post_body(
    const ushort* __restrict__ A, const int* __restrict__ deg,
    const ushort* __restrict__ WmF, const float* __restrict__ bm,
    const ushort* __restrict__ WgF, const float* __restrict__ bg,
    const float* __restrict__ resid, const float* __restrict__ gamma,
    const float* __restrict__ beta, float* __restrict__ out, int N, int tile, char* mem)
{
    const int t = threadIdx.x, w = t >> 6, l = t & 63;
    const int lr = l & 15, lg = l >> 4;
    char* at = mem;
    char* tt = mem + 16384;
    float2 (*part)[64] = (float2 (*)[64])(mem + 32768);
    float2* lnp = (float2*)(mem + 32768 + 2048);

    const int col0 = w * 32 + lr, col1 = col0 + 16;
    const int r0 = tile << 6;
    stage_b16(A, r0, N, at);
    __syncthreads();

    {
        s16x8 B[2][4];
        load_bfrag_pk(WmF, B, w, l);
        const float bm0 = bm[col0], bm1 = bm[col1];
#pragma unroll
        for (int rt = 0; rt < 4; ++rt) {
            s16x8 af[4];
#pragma unroll
            for (int kb = 0; kb < 4; ++kb)
                af[kb] = read_frag(at, rt * 16 + lr, kb * 32 + 8 * lg);
            const int rbase = r0 + rt * 16 + 4 * lg;
            float rs[4];
#pragma unroll
            for (int j = 0; j < 4; ++j)
                rs[j] = (rbase + j < N) ? 1.0f / fmaxf((float)deg[rbase + j], 1e-8f) : 0.f;
            f32x4 a0 = {0.f, 0.f, 0.f, 0.f}, a1 = {0.f, 0.f, 0.f, 0.f};
#pragma unroll
            for (int kb = 0; kb < 4; ++kb) {
                a0 = __builtin_amdgcn_mfma_f32_16x16x32_bf16(af[kb], B[0][kb], a0, 0, 0, 0);
                a1 = __builtin_amdgcn_mfma_f32_16x16x32_bf16(af[kb], B[1][kb], a1, 0, 0, 0);
            }
#pragma unroll
            for (int j = 0; j < 4; ++j) {
                *(ushort*)(tt + swz(rt * 16 + 4 * lg + j, col0)) = f2b(a0[j] * rs[j] + bm0);
                *(ushort*)(tt + swz(rt * 16 + 4 * lg + j, col1)) = f2b(a1[j] * rs[j] + bm1);
            }
        }
    }
    __syncthreads();

    float v[4][2][4];
    {
        s16x8 B[2][4];
        load_bfrag_pk(WgF, B, w, l);
        const float bg0 = bg[col0], bg1 = bg[col1];
#pragma unroll
        for (int rt = 0; rt < 4; ++rt) {
            s16x8 af[4];
#pragma unroll
            for (int kb = 0; kb < 4; ++kb)
                af[kb] = read_frag(tt, rt * 16 + lr, kb * 32 + 8 * lg);
            const int rbase = r0 + rt * 16 + 4 * lg;
            f32x4 a0 = {0.f, 0.f, 0.f, 0.f}, a1 = {0.f, 0.f, 0.f, 0.f};
#pragma unroll
            for (int kb = 0; kb < 4; ++kb) {
                a0 = __builtin_amdgcn_mfma_f32_16x16x32_bf16(af[kb], B[0][kb], a0, 0, 0, 0);
                a1 = __builtin_amdgcn_mfma_f32_16x16x32_bf16(af[kb], B[1][kb], a1, 0, 0, 0);
            }
#pragma unroll
            for (int j = 0; j < 4; ++j) {
                const bool ok = (rbase + j < N);
                const float rv0 = ok ? resid[(size_t)(rbase + j) * 128 + col0] : 0.f;
                const float rv1 = ok ? resid[(size_t)(rbase + j) * 128 + col1] : 0.f;
                v[rt][0][j] = a0[j] + bg0 + rv0;
                v[rt][1][j] = a1[j] + bg1 + rv1;
            }
        }
    }
#pragma unroll
    for (int rt = 0; rt < 4; ++rt)
#pragma unroll
        for (int j = 0; j < 4; ++j) {
            float s = v[rt][0][j] + v[rt][1][j];
            float q = v[rt][0][j] * v[rt][0][j] + v[rt][1][j] * v[rt][1][j];
            s += __shfl_xor(s, 8); q += __shfl_xor(q, 8);
            s += __shfl_xor(s, 4); q += __shfl_xor(q, 4);
            s += __shfl_xor(s, 2); q += __shfl_xor(q, 2);
            s += __shfl_xor(s, 1); q += __shfl_xor(q, 1);
            if (lr == 0) part[w][rt * 16 + 4 * lg + j] = make_float2(s, q);
        }
    __syncthreads();
    if (t < 64) {
        const float S = part[0][t].x + part[1][t].x + part[2][t].x + part[3][t].x;
        const float Qq = part[0][t].y + part[1][t].y + part[2][t].y + part[3][t].y;
        const float mu = S * (1.f / 128.f);
        const float var = Qq * (1.f / 128.f) - mu * mu;
        lnp[t] = make_float2(mu, rsqrtf(var + 1e-5f));
    }
    __syncthreads();
    const float g0 = gamma[col0], g1 = gamma[col1];
    const float be0 = beta[col0], be1 = beta[col1];
#pragma unroll
    for (int rt = 0; rt < 4; ++rt) {
        const int rbase = r0 + rt * 16 + 4 * lg;
#pragma unroll
        for (int j = 0; j < 4; ++j) {
            const float2 mp = lnp[rt * 16 + 4 * lg + j];
            if (rbase + j < N) {
                out[(size_t)(rbase + j) * 128 + col0] = (v[rt][0][j] - mp.x) * mp.y * g0 + be0;
                out[(size_t)(rbase + j) * 128 + col1] = (v[rt][1][j] - mp.x) * mp.y * g1 + be1;
            }
        }
    }
}

__global__ __launch_bounds__(256) void post2_kernel(
    const ushort* __restrict__ msgA, const int* __restrict__ cnt_i,
    const ushort* __restrict__ wfrag,
    const float* __restrict__ bmi, const float* __restrict__ bgi,
    const float* __restrict__ xi, const float* __restrict__ lngi, const float* __restrict__ lnbi,
    float* __restrict__ out_item, int n_item, int nti,
    const ushort* __restrict__ msgB, const int* __restrict__ cnt_u,
    const float* __restrict__ bmu, const float* __restrict__ bgu,
    const float* __restrict__ xu, const float* __restrict__ lngu, const float* __restrict__ lnbu,
    float* __restrict__ out_user, int n_user)
{
    __shared__ char mem[32768 + 2048 + 512];
    const int b = blockIdx.x;
    if (b < nti)
        post_body(msgA, cnt_i, wfrag + 6 * 16384, bmi, wfrag + 7 * 16384, bgi,
                  xi, lngi, lnbi, out_item, n_item, b, mem);
    else
        post_body(msgB, cnt_u, wfrag + 8 * 16384, bmu, wfrag + 9 * 16384, bgu,
                  xu, lngu, lnbu, out_user, n_user, b - nti, mem);
}

// ---------------------------------------------------------------------------
extern "C" void kernel_launch(void* const* d_in, const int* in_sizes, int n_in,
                              void* d_out, int out_size, void* d_ws, size_t ws_size,
                              hipStream_t stream)
{
    const float* x_user  = (const float*)d_in[0];
    const float* x_item  = (const float*)d_in[1];
    const int*   ei_ui   = (const int*)d_in[2];
    const int*   ei_iu   = (const int*)d_in[3];
    const float* Wk_user = (const float*)d_in[4];
    const float* Wq_user = (const float*)d_in[5];
    const float* Wv_user = (const float*)d_in[6];
    const float* Wk_item = (const float*)d_in[7];
    const float* Wq_item = (const float*)d_in[8];
    const float* Wv_item = (const float*)d_in[9];
    const float* Wa_ui   = (const float*)d_in[10];
    const float* Wa_iu   = (const float*)d_in[11];
    const float* Wm_user = (const float*)d_in[12];
    const float* bm_user = (const float*)d_in[13];
    const float* Wm_item = (const float*)d_in[14];
    const float* bm_item = (const float*)d_in[15];
    const float* Wg_user = (const float*)d_in[16];
    const float* bg_user = (const float*)d_in[17];
    const float* Wg_item = (const float*)d_in[18];
    const float* bg_item = (const float*)d_in[19];
    const float* lng_user = (const float*)d_in[20];
    const float* lnb_user = (const float*)d_in[21];
    const float* lng_item = (const float*)d_in[22];
    const float* lnb_item = (const float*)d_in[23];

    const int n_user = in_sizes[0] / DIM;
    const int n_item = in_sizes[1] / DIM;
    const int E = in_sizes[2] / 2;
    const int nmax = (n_user > n_item) ? n_user : n_item;
    const int ntot = n_user + n_item;
    const size_t nf = (size_t)nmax * DIM;

    ushort* Ku   = (ushort*)d_ws;
    ushort* Qu   = Ku + nf;
    ushort* Vu   = Qu + nf;
    ushort* Ki   = Vu + nf;
    ushort* Qi   = Ki + nf;
    ushort* Vi   = Qi + nf;
    ushort* msgA = Vi + nf;
    ushort* msgB = msgA + nf;
    float* kwa_u = (float*)(msgB + nf);
    float* kwa_i = kwa_u + (size_t)nmax * 4;
    int* cnt     = (int*)(kwa_i + (size_t)nmax * 4);  // [ntot] items then users
    int* cursor  = cnt + ntot;                        // [4]
    int* basep   = cursor + 4;                        // [ntot]
    int* fill    = basep + ntot;                      // [ntot]
    ushort* bucket16 = (ushort*)(fill + ntot);        // [2E]
    ushort* wfrag    = bucket16 + 2 * (size_t)E;      // [10*16384]

    float* out_user = (float*)d_out;
    float* out_item = out_user + (size_t)n_user * DIM;

    const dim3 blk(256);
    const int ntu = (n_user + 63) / 64, nti = (n_item + 63) / 64;
    const int histB = (2 * E + 255) / 256;

    hipMemsetAsync(cnt, 0, ((size_t)ntot + 4) * sizeof(int), stream);

    WPtrs wp;
    wp.w[0] = Wk_user; wp.w[1] = Wq_user; wp.w[2] = Wv_user;
    wp.w[3] = Wk_item; wp.w[4] = Wq_item; wp.w[5] = Wv_item;
    wp.w[6] = Wm_item; wp.w[7] = Wg_item;
    wp.w[8] = Wm_user; wp.w[9] = Wg_user;
    prep_hist<<<80 + histB, blk, 0, stream>>>(wp, wfrag, ei_ui + E, ei_iu + E, cnt, n_item, E);

    proj_both<<<ntu + nti, blk, 0, stream>>>(
        x_user, wfrag, Wa_ui, Ku, Qu, Vu, kwa_u, n_user, ntu,
        x_item, Wa_iu, Ki, Qi, Vi, kwa_i, n_item);

    alloc_kernel<<<(ntot + 255) / 256, blk, 0, stream>>>(cnt, basep, fill, cursor, ntot);

    const int aggB = (ntot * 4 + 255) / 256;
    if (nmax <= 65535) {
        scatter_kernel<ushort><<<histB, blk, 0, stream>>>(ei_ui, ei_iu, fill, bucket16, n_item, E);
        agg4_kernel<ushort><<<aggB, blk, 0, stream>>>(
            basep, cnt, (const ushort*)bucket16,
            Ku, Qi, Vu, kwa_u, msgA,
            Ki, Qu, Vi, kwa_i, msgB,
            n_item, ntot);
    } else {
        scatter_kernel<int><<<histB, blk, 0, stream>>>(ei_ui, ei_iu, fill, (int*)bucket16, n_item, E);
        agg4_kernel<int><<<aggB, blk, 0, stream>>>(
            basep, cnt, (const int*)bucket16,
            Ku, Qi, Vu, kwa_u, msgA,
            Ki, Qu, Vi, kwa_i, msgB,
            n_item, ntot);
    }

    post2_kernel<<<nti + ntu, blk, 0, stream>>>(
        msgA, cnt, wfrag, bm_item, bg_item, x_item, lng_item, lnb_item, out_item, n_item, nti,
        msgB, cnt + n_item, bm_user, bg_user, x_user, lng_user, lnb_user, out_user, n_user);
}

// Round 9
// 290.754 us; speedup vs baseline: 1.2543x; 1.0534x over previous
//
#include <hip/hip_runtime.h>
#include <hip/hip_bf16.h>

#define DIM 128

typedef short s16x8 __attribute__((ext_vector_type(8)));
typedef float f32x4 __attribute__((ext_vector_type(4)));

__device__ __forceinline__ ushort f2b(float f) {
    __hip_bfloat16 h = __float2bfloat16(f);
    return *reinterpret_cast<ushort*>(&h);
}
__device__ __forceinline__ uint pk2(float a, float b) {
    return (uint)f2b(a) | ((uint)f2b(b) << 16);
}
__device__ __forceinline__ float bl(uint u) { return __uint_as_float(u << 16); }
__device__ __forceinline__ float bh(uint u) { return __uint_as_float(u & 0xffff0000u); }

// Swizzled byte address inside a [rows][128 bf16] LDS tile (256B rows).
__device__ __forceinline__ int swz(int row, int kelem) {
    int b = row * 256 + kelem * 2;
    return b ^ ((row & 7) << 4);
}
__device__ __forceinline__ s16x8 read_frag(const char* lds, int row, int k0) {
    return *(const s16x8*)(lds + swz(row, k0));
}

// ---------------------------------------------------------------------------
// prep_hist: [0,80) blocks: weight frag-pack; rest: degree histogram.
// ---------------------------------------------------------------------------
struct WPtrs { const float* w[10]; };

__global__ __launch_bounds__(256) void prep_hist(
    WPtrs p, ushort* __restrict__ out,
    const int* __restrict__ dst_i, const int* __restrict__ dst_u,
    int* __restrict__ cnt, int ni, int E)
{
    const int id = blockIdx.x * 256 + threadIdx.x;
    if (id < 20480) {
        const int m = id >> 11;
        const int c = id & 2047;
        const int lane = c & 63;
        const int kb = (c >> 6) & 3;
        const int ct = (c >> 8) & 1;
        const int w = (c >> 9) & 3;
        const int n = w * 32 + ct * 16 + (lane & 15);
        const int k0 = kb * 32 + 8 * (lane >> 4);
        const float* W = p.w[m];
        float v[8];
#pragma unroll
        for (int j = 0; j < 8; ++j) v[j] = W[(size_t)(k0 + j) * 128 + n];
        uint4 u;
        u.x = pk2(v[0], v[1]); u.y = pk2(v[2], v[3]);
        u.z = pk2(v[4], v[5]); u.w = pk2(v[6], v[7]);
        *(uint4*)&out[((size_t)m * 2048 + c) * 8] = u;
    } else {
        const int gid = id - 20480;
        if (gid < E) atomicAdd(&cnt[dst_i[gid]], 1);
        else if (gid < 2 * E) atomicAdd(&cnt[ni + dst_u[gid - E]], 1);
    }
}

// Coalesced fragment load: 8 x 16B per thread from frag-ordered weights.
__device__ __forceinline__ void load_bfrag_pk(const ushort* __restrict__ Wf,
                                              s16x8 B[2][4], int w, int l) {
#pragma unroll
    for (int ct = 0; ct < 2; ++ct)
#pragma unroll
        for (int kb = 0; kb < 4; ++kb)
            B[ct][kb] = *(const s16x8*)&Wf[(size_t)(((w * 2 + ct) * 4 + kb) * 64 + l) * 8];
}

__device__ __forceinline__ void stage_f32(const float* __restrict__ src, int r0, int N, char* lds) {
    const int t = threadIdx.x;
    const int r = t >> 2;
    const int k0 = (t & 3) * 32;
    const int row = r0 + r;
#pragma unroll
    for (int c = 0; c < 4; ++c) {
        uint4 u = make_uint4(0, 0, 0, 0);
        if (row < N) {
            const float4 f0 = *(const float4*)&src[(size_t)row * 128 + k0 + c * 8];
            const float4 f1 = *(const float4*)&src[(size_t)row * 128 + k0 + c * 8 + 4];
            u.x = pk2(f0.x, f0.y); u.y = pk2(f0.z, f0.w);
            u.z = pk2(f1.x, f1.y); u.w = pk2(f1.z, f1.w);
        }
        *(uint4*)(lds + swz(r, k0 + c * 8)) = u;
    }
}

__device__ __forceinline__ void stage_b16(const ushort* __restrict__ src, int r0, int N, char* lds) {
    const int t = threadIdx.x;
    const int r = t >> 2;
    const int k0 = (t & 3) * 32;
    const int row = r0 + r;
#pragma unroll
    for (int c = 0; c < 4; ++c) {
        uint4 u = make_uint4(0, 0, 0, 0);
        if (row < N) u = *(const uint4*)&src[(size_t)row * 128 + k0 + c * 8];
        *(uint4*)(lds + swz(r, k0 + c * 8)) = u;
    }
}

// ---------------------------------------------------------------------------
// proj3: one block = one (64-row tile, matrix) pair. m=0:K(+kwa), 1:Q, 2:V.
// Consecutive blocks (3 per tile) share the staged x-tile via L2/L3.
// __launch_bounds__(256,4): force VGPR <= 128 (occupancy cliff at 128).
// ---------------------------------------------------------------------------
__global__ __launch_bounds__(256, 4) void proj3(
    const float* __restrict__ xu, const ushort* __restrict__ wfrag,
    const float* __restrict__ Waui,
    ushort* __restrict__ Ku, ushort* __restrict__ Qu, ushort* __restrict__ Vu,
    float* __restrict__ kwa_u, int n_user, int ntu,
    const float* __restrict__ xi,
    const float* __restrict__ Waiu,
    ushort* __restrict__ Ki, ushort* __restrict__ Qi, ushort* __restrict__ Vi,
    float* __restrict__ kwa_i, int n_item)
{
    __shared__ char at[16384];
    __shared__ float kwp[4][64][4];
    const int b = blockIdx.x;
    const int m = b % 3;
    const int tile = b / 3;
    const bool user = tile < ntu;
    const float* x = user ? xu : xi;
    const int N = user ? n_user : n_item;
    const int tl = user ? tile : tile - ntu;
    const ushort* WF = wfrag + (size_t)(user ? m : m + 3) * 16384;
    ushort* O = user ? (m == 0 ? Ku : (m == 1 ? Qu : Vu))
                     : (m == 0 ? Ki : (m == 1 ? Qi : Vi));
    const float* Wa = user ? Waui : Waiu;
    float* kwa = user ? kwa_u : kwa_i;

    const int t = threadIdx.x, w = t >> 6, l = t & 63;
    const int lr = l & 15, lg = l >> 4;
    const int r0 = tl << 6;

    stage_f32(x, r0, N, at);
    __syncthreads();

    const int col0 = w * 32 + lr, col1 = col0 + 16;
    s16x8 B[2][4];
    load_bfrag_pk(WF, B, w, l);

    if (m == 0) {
        const float4 waA = *(const float4*)&Wa[col0 * 4];
        const float4 waB = *(const float4*)&Wa[col1 * 4];
#pragma unroll
        for (int rt = 0; rt < 4; ++rt) {
            s16x8 af[4];
#pragma unroll
            for (int kb = 0; kb < 4; ++kb)
                af[kb] = read_frag(at, rt * 16 + lr, kb * 32 + 8 * lg);
            const int rbase = r0 + rt * 16 + 4 * lg;
            f32x4 a0 = {0.f, 0.f, 0.f, 0.f}, a1 = {0.f, 0.f, 0.f, 0.f};
#pragma unroll
            for (int kb = 0; kb < 4; ++kb) {
                a0 = __builtin_amdgcn_mfma_f32_16x16x32_bf16(af[kb], B[0][kb], a0, 0, 0, 0);
                a1 = __builtin_amdgcn_mfma_f32_16x16x32_bf16(af[kb], B[1][kb], a1, 0, 0, 0);
            }
#pragma unroll
            for (int j = 0; j < 4; ++j) {
                if (rbase + j < N) {
                    O[(size_t)(rbase + j) * 128 + col0] = f2b(a0[j]);
                    O[(size_t)(rbase + j) * 128 + col1] = f2b(a1[j]);
                }
            }
#pragma unroll
            for (int j = 0; j < 4; ++j) {
                float p0 = a0[j] * waA.x + a1[j] * waB.x;
                float p1 = a0[j] * waA.y + a1[j] * waB.y;
                float p2 = a0[j] * waA.z + a1[j] * waB.z;
                float p3 = a0[j] * waA.w + a1[j] * waB.w;
#pragma unroll
                for (int off = 8; off; off >>= 1) {
                    p0 += __shfl_xor(p0, off);
                    p1 += __shfl_xor(p1, off);
                    p2 += __shfl_xor(p2, off);
                    p3 += __shfl_xor(p3, off);
                }
                if (lr == 0) {
                    kwp[w][rt * 16 + 4 * lg + j][0] = p0;
                    kwp[w][rt * 16 + 4 * lg + j][1] = p1;
                    kwp[w][rt * 16 + 4 * lg + j][2] = p2;
                    kwp[w][rt * 16 + 4 * lg + j][3] = p3;
                }
            }
        }
        __syncthreads();
        if (t < 64 && r0 + t < N) {
            const float s0 = kwp[0][t][0] + kwp[1][t][0] + kwp[2][t][0] + kwp[3][t][0];
            const float s1 = kwp[0][t][1] + kwp[1][t][1] + kwp[2][t][1] + kwp[3][t][1];
            const float s2 = kwp[0][t][2] + kwp[1][t][2] + kwp[2][t][2] + kwp[3][t][2];
            const float s3 = kwp[0][t][3] + kwp[1][t][3] + kwp[2][t][3] + kwp[3][t][3];
            *(float4*)&kwa[(size_t)(r0 + t) * 4] = make_float4(s0, s1, s2, s3);
        }
    } else {
#pragma unroll
        for (int rt = 0; rt < 4; ++rt) {
            s16x8 af[4];
#pragma unroll
            for (int kb = 0; kb < 4; ++kb)
                af[kb] = read_frag(at, rt * 16 + lr, kb * 32 + 8 * lg);
            const int rbase = r0 + rt * 16 + 4 * lg;
            f32x4 a0 = {0.f, 0.f, 0.f, 0.f}, a1 = {0.f, 0.f, 0.f, 0.f};
#pragma unroll
            for (int kb = 0; kb < 4; ++kb) {
                a0 = __builtin_amdgcn_mfma_f32_16x16x32_bf16(af[kb], B[0][kb], a0, 0, 0, 0);
                a1 = __builtin_amdgcn_mfma_f32_16x16x32_bf16(af[kb], B[1][kb], a1, 0, 0, 0);
            }
#pragma unroll
            for (int j = 0; j < 4; ++j) {
                if (rbase + j < N) {
                    O[(size_t)(rbase + j) * 128 + col0] = f2b(a0[j]);
                    O[(size_t)(rbase + j) * 128 + col1] = f2b(a1[j]);
                }
            }
        }
    }
}

// ---------------------------------------------------------------------------
__global__ __launch_bounds__(256) void alloc_kernel(
    const int* __restrict__ cnt, int* __restrict__ base,
    int* __restrict__ fill, int* __restrict__ cursor, int n)
{
    const int d = blockIdx.x * blockDim.x + threadIdx.x;
    const int lane = threadIdx.x & 63;
    int c = (d < n) ? cnt[d] : 0;
    int sc = c;
#pragma unroll
    for (int off = 1; off < 64; off <<= 1) {
        int t = __shfl_up(sc, off);
        if (lane >= off) sc += t;
    }
    const int total = __shfl(sc, 63);
    int wb = 0;
    if (lane == 63) wb = atomicAdd(cursor, total);
    wb = __shfl(wb, 63);
    if (d < n) {
        const int b = wb + sc - c;
        base[d] = b;
        fill[d] = b;
    }
}

template<typename IT>
__global__ __launch_bounds__(256) void scatter_kernel(
    const int* __restrict__ ei_ui, const int* __restrict__ ei_iu,
    int* __restrict__ fill, IT* __restrict__ bucket, int ni, int E)
{
    const int e = blockIdx.x * blockDim.x + threadIdx.x;
    if (e < E) {
        const int pos = atomicAdd(&fill[ei_ui[E + e]], 1);
        bucket[pos] = (IT)ei_ui[e];
    } else if (e < 2 * E) {
        const int pos = atomicAdd(&fill[ni + ei_iu[E + e - E]], 1);
        bucket[pos] = (IT)ei_iu[e - E];
    }
}

// ---------------------------------------------------------------------------
// agg4: one 4-lane group per dst; lane li owns head li = dims [32li, 32li+32).
// ---------------------------------------------------------------------------
__device__ __forceinline__ void unpack8(uint4 u, float* q) {
    q[0] = bl(u.x); q[1] = bh(u.x); q[2] = bl(u.y); q[3] = bh(u.y);
    q[4] = bl(u.z); q[5] = bh(u.z); q[6] = bl(u.w); q[7] = bh(u.w);
}
__device__ __forceinline__ float dot8(uint4 u, const float* q) {
    return bl(u.x) * q[0] + bh(u.x) * q[1] + bl(u.y) * q[2] + bh(u.y) * q[3]
         + bl(u.z) * q[4] + bh(u.z) * q[5] + bl(u.w) * q[6] + bh(u.w) * q[7];
}
__device__ __forceinline__ void acc8(uint4 u, float a, float* acc) {
    acc[0] += a * bl(u.x); acc[1] += a * bh(u.x);
    acc[2] += a * bl(u.y); acc[3] += a * bh(u.y);
    acc[4] += a * bl(u.z); acc[5] += a * bh(u.z);
    acc[6] += a * bl(u.w); acc[7] += a * bh(u.w);
}

template<typename IT>
__global__ __launch_bounds__(256) void agg4_kernel(
    const int* __restrict__ base, const int* __restrict__ cnt, const IT* __restrict__ bsrc,
    const ushort* __restrict__ Ku, const ushort* __restrict__ Qi, const ushort* __restrict__ Vu,
    const float* __restrict__ kwa_u, ushort* __restrict__ msgA,
    const ushort* __restrict__ Ki, const ushort* __restrict__ Qu, const ushort* __restrict__ Vi,
    const float* __restrict__ kwa_i, ushort* __restrict__ msgB,
    int n_item, int ntot)
{
    const int gid = (int)((blockIdx.x * blockDim.x + threadIdx.x) >> 2);
    if (gid >= ntot) return;
    const int li = threadIdx.x & 3;
    const bool item_side = gid < n_item;
    const int d = item_side ? gid : gid - n_item;
    const ushort* K  = item_side ? Ku : Ki;
    const ushort* Q  = item_side ? Qi : Qu;
    const ushort* V  = item_side ? Vu : Vi;
    const float* kwa = item_side ? kwa_u : kwa_i;
    ushort* msg      = item_side ? msgA : msgB;

    const float inv = 0.17677669529663687f;   // 1/sqrt(32)

    float q[32];
    {
        const uint4* qp = (const uint4*)&Q[(size_t)d * 128 + li * 32];
#pragma unroll
        for (int m = 0; m < 4; ++m) unpack8(qp[m], &q[m * 8]);
    }
    float acc[32];
#pragma unroll
    for (int m = 0; m < 32; ++m) acc[m] = 0.f;

    const int b = base[gid], c = cnt[gid];
    int s = (c > 0) ? (int)bsrc[b] : 0;
    for (int i = 0; i < c; ++i) {
        const int snext = (i + 1 < c) ? (int)bsrc[b + i + 1] : s;
        const uint4* kp = (const uint4*)&K[(size_t)s * 128 + li * 32];
        const uint4* vp = (const uint4*)&V[(size_t)s * 128 + li * 32];
        const uint4 k0 = kp[0], k1 = kp[1], k2 = kp[2], k3 = kp[3];
        const uint4 v0 = vp[0], v1 = vp[1], v2 = vp[2], v3 = vp[3];
        const float kw = kwa[(size_t)s * 4 + li];

        float p = dot8(k0, &q[0]) + dot8(k1, &q[8]) + dot8(k2, &q[16]) + dot8(k3, &q[24]);
        const float e = __expf(p * inv + kw);
        float es = e + __shfl_xor(e, 1);
        es += __shfl_xor(es, 2);
        const float att = __fdividef(e, es);

        acc8(v0, att, &acc[0]);
        acc8(v1, att, &acc[8]);
        acc8(v2, att, &acc[16]);
        acc8(v3, att, &acc[24]);
        s = snext;
    }

    uint4* mp = (uint4*)&msg[(size_t)d * 128 + li * 32];
#pragma unroll
    for (int m = 0; m < 4; ++m) {
        uint4 o;
        o.x = pk2(acc[m * 8 + 0], acc[m * 8 + 1]);
        o.y = pk2(acc[m * 8 + 2], acc[m * 8 + 3]);
        o.z = pk2(acc[m * 8 + 4], acc[m * 8 + 5]);
        o.w = pk2(acc[m * 8 + 6], acc[m * 8 + 7]);
        mp[m] = o;
    }
}

// ---------------------------------------------------------------------------
// post body: LN(((A@Wm)*rs+bm)@Wg + bg + resid)*g + b. launch_bounds(256,4).
// ---------------------------------------------------------------------------
__device__ void post_body(
    const ushort* __restrict__ A, const int* __restrict__ deg,
    const ushort* __restrict__ WmF, const float* __restrict__ bm,
    const ushort* __restrict__ WgF, const float* __restrict__ bg,
    const float* __restrict__ resid, const float* __restrict__ gamma,
    const float* __restrict__ beta, float* __restrict__ out, int N, int tile, char* mem)
{
    const int t = threadIdx.x, w = t >> 6, l = t & 63;
    const int lr = l & 15, lg = l >> 4;
    char* at = mem;
    char* tt = mem + 16384;
    float2 (*part)[64] = (float2 (*)[64])(mem + 32768);
    float2* lnp = (float2*)(mem + 32768 + 2048);

    const int col0 = w * 32 + lr, col1 = col0 + 16;
    const int r0 = tile << 6;
    stage_b16(A, r0, N, at);
    __syncthreads();

    {
        s16x8 B[2][4];
        load_bfrag_pk(WmF, B, w, l);
        const float bm0 = bm[col0], bm1 = bm[col1];
#pragma unroll
        for (int rt = 0; rt < 4; ++rt) {
            s16x8 af[4];
#pragma unroll
            for (int kb = 0; kb < 4; ++kb)
                af[kb] = read_frag(at, rt * 16 + lr, kb * 32 + 8 * lg);
            const int rbase = r0 + rt * 16 + 4 * lg;
            float rs[4];
#pragma unroll
            for (int j = 0; j < 4; ++j)
                rs[j] = (rbase + j < N) ? 1.0f / fmaxf((float)deg[rbase + j], 1e-8f) : 0.f;
            f32x4 a0 = {0.f, 0.f, 0.f, 0.f}, a1 = {0.f, 0.f, 0.f, 0.f};
#pragma unroll
            for (int kb = 0; kb < 4; ++kb) {
                a0 = __builtin_amdgcn_mfma_f32_16x16x32_bf16(af[kb], B[0][kb], a0, 0, 0, 0);
                a1 = __builtin_amdgcn_mfma_f32_16x16x32_bf16(af[kb], B[1][kb], a1, 0, 0, 0);
            }
#pragma unroll
            for (int j = 0; j < 4; ++j) {
                *(ushort*)(tt + swz(rt * 16 + 4 * lg + j, col0)) = f2b(a0[j] * rs[j] + bm0);
                *(ushort*)(tt + swz(rt * 16 + 4 * lg + j, col1)) = f2b(a1[j] * rs[j] + bm1);
            }
        }
    }
    __syncthreads();

    float v[4][2][4];
    {
        s16x8 B[2][4];
        load_bfrag_pk(WgF, B, w, l);
        const float bg0 = bg[col0], bg1 = bg[col1];
#pragma unroll
        for (int rt = 0; rt < 4; ++rt) {
            s16x8 af[4];
#pragma unroll
            for (int kb = 0; kb < 4; ++kb)
                af[kb] = read_frag(tt, rt * 16 + lr, kb * 32 + 8 * lg);
            const int rbase = r0 + rt * 16 + 4 * lg;
            f32x4 a0 = {0.f, 0.f, 0.f, 0.f}, a1 = {0.f, 0.f, 0.f, 0.f};
#pragma unroll
            for (int kb = 0; kb < 4; ++kb) {
                a0 = __builtin_amdgcn_mfma_f32_16x16x32_bf16(af[kb], B[0][kb], a0, 0, 0, 0);
                a1 = __builtin_amdgcn_mfma_f32_16x16x32_bf16(af[kb], B[1][kb], a1, 0, 0, 0);
            }
#pragma unroll
            for (int j = 0; j < 4; ++j) {
                const bool ok = (rbase + j < N);
                const float rv0 = ok ? resid[(size_t)(rbase + j) * 128 + col0] : 0.f;
                const float rv1 = ok ? resid[(size_t)(rbase + j) * 128 + col1] : 0.f;
                v[rt][0][j] = a0[j] + bg0 + rv0;
                v[rt][1][j] = a1[j] + bg1 + rv1;
            }
        }
    }
#pragma unroll
    for (int rt = 0; rt < 4; ++rt)
#pragma unroll
        for (int j = 0; j < 4; ++j) {
            float s = v[rt][0][j] + v[rt][1][j];
            float q = v[rt][0][j] * v[rt][0][j] + v[rt][1][j] * v[rt][1][j];
            s += __shfl_xor(s, 8); q += __shfl_xor(q, 8);
            s += __shfl_xor(s, 4); q += __shfl_xor(q, 4);
            s += __shfl_xor(s, 2); q += __shfl_xor(q, 2);
            s += __shfl_xor(s, 1); q += __shfl_xor(q, 1);
            if (lr == 0) part[w][rt * 16 + 4 * lg + j] = make_float2(s, q);
        }
    __syncthreads();
    if (t < 64) {
        const float S = part[0][t].x + part[1][t].x + part[2][t].x + part[3][t].x;
        const float Qq = part[0][t].y + part[1][t].y + part[2][t].y + part[3][t].y;
        const float mu = S * (1.f / 128.f);
        const float var = Qq * (1.f / 128.f) - mu * mu;
        lnp[t] = make_float2(mu, rsqrtf(var + 1e-5f));
    }
    __syncthreads();
    const float g0 = gamma[col0], g1 = gamma[col1];
    const float be0 = beta[col0], be1 = beta[col1];
#pragma unroll
    for (int rt = 0; rt < 4; ++rt) {
        const int rbase = r0 + rt * 16 + 4 * lg;
#pragma unroll
        for (int j = 0; j < 4; ++j) {
            const float2 mp = lnp[rt * 16 + 4 * lg + j];
            if (rbase + j < N) {
                out[(size_t)(rbase + j) * 128 + col0] = (v[rt][0][j] - mp.x) * mp.y * g0 + be0;
                out[(size_t)(rbase + j) * 128 + col1] = (v[rt][1][j] - mp.x) * mp.y * g1 + be1;
            }
        }
    }
}

__global__ __launch_bounds__(256, 4) void post2_kernel(
    const ushort* __restrict__ msgA, const int* __restrict__ cnt_i,
    const ushort* __restrict__ wfrag,
    const float* __restrict__ bmi, const float* __restrict__ bgi,
    const float* __restrict__ xi, const float* __restrict__ lngi, const float* __restrict__ lnbi,
    float* __restrict__ out_item, int n_item, int nti,
    const ushort* __restrict__ msgB, const int* __restrict__ cnt_u,
    const float* __restrict__ bmu, const float* __restrict__ bgu,
    const float* __restrict__ xu, const float* __restrict__ lngu, const float* __restrict__ lnbu,
    float* __restrict__ out_user, int n_user)
{
    __shared__ char mem[32768 + 2048 + 512];
    const int b = blockIdx.x;
    if (b < nti)
        post_body(msgA, cnt_i, wfrag + 6 * 16384, bmi, wfrag + 7 * 16384, bgi,
                  xi, lngi, lnbi, out_item, n_item, b, mem);
    else
        post_body(msgB, cnt_u, wfrag + 8 * 16384, bmu, wfrag + 9 * 16384, bgu,
                  xu, lngu, lnbu, out_user, n_user, b - nti, mem);
}

// ---------------------------------------------------------------------------
extern "C" void kernel_launch(void* const* d_in, const int* in_sizes, int n_in,
                              void* d_out, int out_size, void* d_ws, size_t ws_size,
                              hipStream_t stream)
{
    const float* x_user  = (const float*)d_in[0];
    const float* x_item  = (const float*)d_in[1];
    const int*   ei_ui   = (const int*)d_in[2];
    const int*   ei_iu   = (const int*)d_in[3];
    const float* Wk_user = (const float*)d_in[4];
    const float* Wq_user = (const float*)d_in[5];
    const float* Wv_user = (const float*)d_in[6];
    const float* Wk_item = (const float*)d_in[7];
    const float* Wq_item = (const float*)d_in[8];
    const float* Wv_item = (const float*)d_in[9];
    const float* Wa_ui   = (const float*)d_in[10];
    const float* Wa_iu   = (const float*)d_in[11];
    const float* Wm_user = (const float*)d_in[12];
    const float* bm_user = (const float*)d_in[13];
    const float* Wm_item = (const float*)d_in[14];
    const float* bm_item = (const float*)d_in[15];
    const float* Wg_user = (const float*)d_in[16];
    const float* bg_user = (const float*)d_in[17];
    const float* Wg_item = (const float*)d_in[18];
    const float* bg_item = (const float*)d_in[19];
    const float* lng_user = (const float*)d_in[20];
    const float* lnb_user = (const float*)d_in[21];
    const float* lng_item = (const float*)d_in[22];
    const float* lnb_item = (const float*)d_in[23];

    const int n_user = in_sizes[0] / DIM;
    const int n_item = in_sizes[1] / DIM;
    const int E = in_sizes[2] / 2;
    const int nmax = (n_user > n_item) ? n_user : n_item;
    const int ntot = n_user + n_item;
    const size_t nf = (size_t)nmax * DIM;

    ushort* Ku   = (ushort*)d_ws;
    ushort* Qu   = Ku + nf;
    ushort* Vu   = Qu + nf;
    ushort* Ki   = Vu + nf;
    ushort* Qi   = Ki + nf;
    ushort* Vi   = Qi + nf;
    ushort* msgA = Vi + nf;
    ushort* msgB = msgA + nf;
    float* kwa_u = (float*)(msgB + nf);
    float* kwa_i = kwa_u + (size_t)nmax * 4;
    int* cnt     = (int*)(kwa_i + (size_t)nmax * 4);  // [ntot] items then users
    int* cursor  = cnt + ntot;                        // [4]
    int* basep   = cursor + 4;                        // [ntot]
    int* fill    = basep + ntot;                      // [ntot]
    ushort* bucket16 = (ushort*)(fill + ntot);        // [2E]
    ushort* wfrag    = bucket16 + 2 * (size_t)E;      // [10*16384]

    float* out_user = (float*)d_out;
    float* out_item = out_user + (size_t)n_user * DIM;

    const dim3 blk(256);
    const int ntu = (n_user + 63) / 64, nti = (n_item + 63) / 64;
    const int histB = (2 * E + 255) / 256;

    hipMemsetAsync(cnt, 0, ((size_t)ntot + 4) * sizeof(int), stream);

    WPtrs wp;
    wp.w[0] = Wk_user; wp.w[1] = Wq_user; wp.w[2] = Wv_user;
    wp.w[3] = Wk_item; wp.w[4] = Wq_item; wp.w[5] = Wv_item;
    wp.w[6] = Wm_item; wp.w[7] = Wg_item;
    wp.w[8] = Wm_user; wp.w[9] = Wg_user;
    prep_hist<<<80 + histB, blk, 0, stream>>>(wp, wfrag, ei_ui + E, ei_iu + E, cnt, n_item, E);

    proj3<<<3 * (ntu + nti), blk, 0, stream>>>(
        x_user, wfrag, Wa_ui, Ku, Qu, Vu, kwa_u, n_user, ntu,
        x_item, Wa_iu, Ki, Qi, Vi, kwa_i, n_item);

    alloc_kernel<<<(ntot + 255) / 256, blk, 0, stream>>>(cnt, basep, fill, cursor, ntot);

    const int aggB = (ntot * 4 + 255) / 256;
    if (nmax <= 65535) {
        scatter_kernel<ushort><<<histB, blk, 0, stream>>>(ei_ui, ei_iu, fill, bucket16, n_item, E);
        agg4_kernel<ushort><<<aggB, blk, 0, stream>>>(
            basep, cnt, (const ushort*)bucket16,
            Ku, Qi, Vu, kwa_u, msgA,
            Ki, Qu, Vi, kwa_i, msgB,
            n_item, ntot);
    } else {
        scatter_kernel<int><<<histB, blk, 0, stream>>>(ei_ui, ei_iu, fill, (int*)bucket16, n_item, E);
        agg4_kernel<int><<<aggB, blk, 0, stream>>>(
            basep, cnt, (const int*)bucket16,
            Ku, Qi, Vu, kwa_u, msgA,
            Ki, Qu, Vi, kwa_i, msgB,
            n_item, ntot);
    }

    post2_kernel<<<nti + ntu, blk, 0, stream>>>(
        msgA, cnt, wfrag, bm_item, bg_item, x_item, lng_item, lnb_item, out_item, n_item, nti,
        msgB, cnt + n_item, bm_user, bg_user, x_user, lng_user, lnb_user, out_user, n_user);
}